// Round 5
// baseline (2439.163 us; speedup 1.0000x reference)
//
#include <hip/hip_runtime.h>
#include <hip/hip_bf16.h>
#include <math.h>

#define B_ 16
#define T_ 256
#define D_ 1024
#define H_ 1024
#define S_ 16
#define SCALE_ (1.0f/32.0f)   // 1/sqrt(1024)

typedef __attribute__((ext_vector_type(8))) short short8v;
typedef __attribute__((ext_vector_type(4))) float f32x4;

__device__ __forceinline__ float sigm(float x) { return 1.f / (1.f + expf(-x)); }

__device__ __forceinline__ ushort f2b(float v) {
  __hip_bfloat16 h = __float2bfloat16(v);
  return *reinterpret_cast<ushort*>(&h);
}
__device__ __forceinline__ float b2f(ushort u) {
  union { unsigned u32; float f; } x; x.u32 = ((unsigned)u) << 16; return x.f;
}

__device__ __forceinline__ void glds16(const void* g, void* l) {
  __builtin_amdgcn_global_load_lds((const __attribute__((address_space(1))) void*)g,
                                   (__attribute__((address_space(3))) void*)l, 16, 0, 0);
}

// one wave polls 64 per-producer flag words (lane l -> word l) until all set
__device__ __forceinline__ void waitflags64(const int* f, int lane) {
  for (;;) {
    int v = __hip_atomic_load(f + lane, __ATOMIC_ACQUIRE, __HIP_MEMORY_SCOPE_AGENT);
    if (__all(v != 0)) return;
    __builtin_amdgcn_s_sleep(1);
  }
}

__device__ __forceinline__ float block_sum256(float v) {
  __shared__ float lds[4];
  #pragma unroll
  for (int off = 32; off; off >>= 1) v += __shfl_down(v, off);
  int w = threadIdx.x >> 6;
  if ((threadIdx.x & 63) == 0) lds[w] = v;
  __syncthreads();
  float r = lds[0] + lds[1] + lds[2] + lds[3];
  __syncthreads();
  return r;
}

// ---------------- fp32 -> bf16 convert ----------------
__global__ __launch_bounds__(256)
void cvt_bf16(const float* __restrict__ in, ushort* __restrict__ out, int n)
{
  int i = (blockIdx.x * 256 + threadIdx.x) * 4;
  if (i >= n) return;
  float4 v = *(const float4*)(in + i);
  ushort4 o; o.x = f2b(v.x); o.y = f2b(v.y); o.z = f2b(v.z); o.w = f2b(v.w);
  *(ushort4*)(out + i) = o;
}

// ---------------- MFMA bf16 GEMM: C = act(ascale * A@W^T + bias) ----------------
template<int ACT, int REMAP>   // ACT: 0 none, 1 relu, 2 sigmoid
__global__ __launch_bounds__(256)
void gemm_bf16(const ushort* __restrict__ A, const ushort* __restrict__ W,
               const float* __restrict__ bias,
               float* __restrict__ Cf, ushort* __restrict__ Cb,
               int M, int N, int K, float ascale)
{
  __shared__ char As[16384];
  __shared__ char Bs[16384];
  const int tid = threadIdx.x;
  const int w = tid >> 6, l = tid & 63;
  const int m0 = blockIdx.y * 128, n0 = blockIdx.x * 128;
  const int wm = w >> 1, wn = w & 1;
  const int srow = l >> 3;
  const int sbyte = ((l & 7) * 16) ^ (srow << 4);
  f32x4 acc[4][4];
  #pragma unroll
  for (int i = 0; i < 4; ++i)
    #pragma unroll
    for (int j = 0; j < 4; ++j) acc[i][j] = (f32x4){0.f, 0.f, 0.f, 0.f};

  for (int k0 = 0; k0 < K; k0 += 64) {
    __syncthreads();
    #pragma unroll
    for (int c = 0; c < 4; ++c) {
      int ca = w * 4 + c;
      int r = ca * 8 + srow;
      glds16((const char*)A + (((size_t)(m0 + r) * K + k0) << 1) + sbyte, As + ca * 1024);
      glds16((const char*)W + (((size_t)(n0 + r) * K + k0) << 1) + sbyte, Bs + ca * 1024);
    }
    __syncthreads();
    #pragma unroll
    for (int ks = 0; ks < 2; ++ks) {
      short8v a[4], b[4];
      int qb = ks * 64 + (l >> 4) * 16;
      #pragma unroll
      for (int i = 0; i < 4; ++i) {
        int ra = wm * 64 + i * 16 + (l & 15);
        a[i] = *(const short8v*)(As + ra * 128 + (qb ^ ((ra & 7) << 4)));
        int rb = wn * 64 + i * 16 + (l & 15);
        b[i] = *(const short8v*)(Bs + rb * 128 + (qb ^ ((rb & 7) << 4)));
      }
      #pragma unroll
      for (int i = 0; i < 4; ++i)
        #pragma unroll
        for (int j = 0; j < 4; ++j)
          acc[i][j] = __builtin_amdgcn_mfma_f32_16x16x32_bf16(a[i], b[j], acc[i][j], 0, 0, 0);
    }
  }
  #pragma unroll
  for (int i = 0; i < 4; ++i) {
    #pragma unroll
    for (int j = 0; j < 4; ++j) {
      int n = n0 + wn * 64 + j * 16 + (l & 15);
      float bv = bias ? bias[n] : 0.f;
      #pragma unroll
      for (int q = 0; q < 4; ++q) {
        int m = m0 + wm * 64 + i * 16 + (l >> 4) * 4 + q;
        float v = acc[i][j][q] * ascale + bv;
        if (ACT == 1) v = fmaxf(v, 0.f);
        if (ACT == 2) v = sigm(v);
        size_t off = REMAP ? ((size_t)((m & 255) * 16 + (m >> 8)) * N + n)
                           : ((size_t)m * N + n);
        if (Cf) Cf[off] = v;
        if (Cb) Cb[off] = f2b(v);
      }
    }
  }
}

// ---------------- LayerNorm+relu: f32 in -> bf16 out ----------------
__global__ __launch_bounds__(256)
void ln_relu_bf16(const float* __restrict__ X, const float* __restrict__ g,
                  const float* __restrict__ be, ushort* __restrict__ out)
{
  size_t row = blockIdx.x;
  const float4* p = (const float4*)(X + row * 1024);
  int tid = threadIdx.x;
  float4 v = p[tid];
  float s = block_sum256(v.x + v.y + v.z + v.w);
  float mean = s * (1.f / 1024.f);
  float dx = v.x - mean, dy = v.y - mean, dz = v.z - mean, dw = v.w - mean;
  float ss = block_sum256(dx*dx + dy*dy + dz*dz + dw*dw);
  float r = rsqrtf(ss * (1.f / 1024.f) + 1e-5f);
  int c4 = tid * 4;
  ushort4 o;
  o.x = f2b(fmaxf(dx * r * g[c4+0] + be[c4+0], 0.f));
  o.y = f2b(fmaxf(dy * r * g[c4+1] + be[c4+1], 0.f));
  o.z = f2b(fmaxf(dz * r * g[c4+2] + be[c4+2], 0.f));
  o.w = f2b(fmaxf(dw * r * g[c4+3] + be[c4+3], 0.f));
  *(ushort4*)(out + row * 1024 + c4) = o;
}

// final LN+relu: rows (t*B+b) f32 -> out [b][t][h] f32
__global__ __launch_bounds__(256)
void ln_relu_final(const float* __restrict__ F, const float* __restrict__ g,
                   const float* __restrict__ be, float* __restrict__ out)
{
  int row = blockIdx.x;           // t*16 + b
  int t = row >> 4, b = row & 15;
  const float4* p = (const float4*)(F + (size_t)row * 1024);
  int tid = threadIdx.x;
  float4 v = p[tid];
  float s = block_sum256(v.x + v.y + v.z + v.w);
  float mean = s * (1.f / 1024.f);
  float dx = v.x - mean, dy = v.y - mean, dz = v.z - mean, dw = v.w - mean;
  float ss = block_sum256(dx*dx + dy*dy + dz*dz + dw*dw);
  float r = rsqrtf(ss * (1.f / 1024.f) + 1e-5f);
  int c4 = tid * 4;
  float4 o;
  o.x = fmaxf(dx * r * g[c4+0] + be[c4+0], 0.f);
  o.y = fmaxf(dy * r * g[c4+1] + be[c4+1], 0.f);
  o.z = fmaxf(dz * r * g[c4+2] + be[c4+2], 0.f);
  o.w = fmaxf(dw * r * g[c4+3] + be[c4+3], 0.f);
  ((float4*)(out + ((size_t)b * T_ + t) * 1024))[tid] = o;
}

// ---------------- persistent cooperative LSTM (all 256 steps) ----------------
// 128 blocks x 512 threads, cooperative launch. Blocks 0..63: layer 0,
// blocks 64..127: layer 1; block owns 16 output cols (all 4 gates).
// Weights in VGPRs, c-state in registers. Cross-block dataflow via write-once
// per-step h buffers (agent-scope stores) + DISTRIBUTED per-producer flag
// words: producer RELEASE-stores its own word (no RMW); one consumer wave
// polls all 64 words lane-parallel with ACQUIRE loads. Flags zeroed per call.
__global__ __launch_bounds__(512)
void lstm_persistent(const ushort* __restrict__ Z0T,   // [T*B,4096] bf16
                     const ushort* __restrict__ whh0,  // [4096,1024]
                     const float* __restrict__ bhh0,
                     const ushort* __restrict__ wih1,  // [4096,1024]
                     const ushort* __restrict__ whh1,  // [4096,1024]
                     const float* __restrict__ bih1,
                     const float* __restrict__ bhh1,
                     ushort* __restrict__ HP,          // [257][16][1024], slot0 zeroed
                     ushort* __restrict__ H1B,         // [256][16][1024]
                     const ushort* __restrict__ ZP,    // 32KB zeros (h1 at t=-1)
                     float* __restrict__ KSUM,         // [S*B,1024] f32
                     int* flag0,                       // [257][64]
                     int* flag1)                       // [256][64]
{
  __shared__ char Ah[65536];
  __shared__ float zs[8][16][16];
  const int tid = threadIdx.x, w = tid >> 6, l = tid & 63;
  const int lm = l & 15, lq = l >> 4;
  const int g = w & 3, kh = w >> 2;
  const int jb = blockIdx.x & 63;
  const int j0 = jb * 16;
  const int eb = tid >> 4, ej = tid & 15, jf = j0 + ej;   // tid<256 only
  float creg = 0.f;
  float br[4];

  if (blockIdx.x < 64) {
    // ================= layer 0 =================
    short8v wreg[16];
    {
      const int n = g * 1024 + j0 + lm;
      const ushort* wb = whh0 + (size_t)n * 1024 + kh * 512 + lq * 8;
      #pragma unroll
      for (int ks = 0; ks < 16; ++ks) wreg[ks] = *(const short8v*)(wb + ks * 32);
    }
    if (tid < 256) {
      #pragma unroll
      for (int gg = 0; gg < 4; ++gg) br[gg] = bhh0[gg * 1024 + jf];
    }
    for (int t = 0; t < T_; ++t) {
      // prefetch Z0 gate pre-activations (static data) before the spin
      float z0v[4];
      if (tid < 256) {
        const ushort* zp = Z0T + ((size_t)t * 16 + eb) * 4096 + jf;
        #pragma unroll
        for (int gg = 0; gg < 4; ++gg) z0v[gg] = b2f(zp[gg * 1024]);
      }
      if (t > 0) {
        if (w == 0) waitflags64(flag0 + (size_t)t * 64, l);
        __syncthreads();
      }
      const ushort* hin = HP + (size_t)t * 16384;
      #pragma unroll
      for (int it = 0; it < 4; ++it) {
        int g1k = w * 4 + it;             // 0..31 (1KB chunks)
        int kc = g1k * 4 + lq;            // 0..127
        int m = lm ^ (kc & 15);
        glds16(hin + (size_t)m * 1024 + kc * 8, Ah + g1k * 1024);
      }
      __syncthreads();
      {
        f32x4 a0 = {0.f,0.f,0.f,0.f}, a1 = {0.f,0.f,0.f,0.f};
        #pragma unroll
        for (int ks = 0; ks < 16; ks += 2) {
          int kc0 = kh * 64 + ks * 4 + lq;
          int kc1 = kc0 + 4;
          short8v f0 = *(const short8v*)(Ah + kc0 * 256 + ((lm ^ (kc0 & 15)) << 4));
          short8v f1 = *(const short8v*)(Ah + kc1 * 256 + ((lm ^ (kc1 & 15)) << 4));
          a0 = __builtin_amdgcn_mfma_f32_16x16x32_bf16(f0, wreg[ks],     a0, 0, 0, 0);
          a1 = __builtin_amdgcn_mfma_f32_16x16x32_bf16(f1, wreg[ks + 1], a1, 0, 0, 0);
        }
        #pragma unroll
        for (int q = 0; q < 4; ++q) zs[w][lq * 4 + q][lm] = a0[q] + a1[q];
      }
      __syncthreads();
      if (tid < 256) {
        float zi = zs[0][eb][ej] + zs[4][eb][ej] + z0v[0] + br[0];
        float zf = zs[1][eb][ej] + zs[5][eb][ej] + z0v[1] + br[1];
        float zg = zs[2][eb][ej] + zs[6][eb][ej] + z0v[2] + br[2];
        float zo = zs[3][eb][ej] + zs[7][eb][ej] + z0v[3] + br[3];
        float cp = sigm(zf) * creg + sigm(zi) * tanhf(zg);
        creg = cp;
        ushort hb = f2b(sigm(zo) * tanhf(cp));
        __hip_atomic_store(HP + (size_t)(t + 1) * 16384 + eb * 1024 + jf, hb,
                           __ATOMIC_RELAXED, __HIP_MEMORY_SCOPE_AGENT);
      }
      __syncthreads();   // all h stores acked at coherence point
      if (tid == 0)
        __hip_atomic_store(flag0 + (size_t)(t + 1) * 64 + jb, 1,
                           __ATOMIC_RELEASE, __HIP_MEMORY_SCOPE_AGENT);
    }
  } else {
    // ================= layer 1 =================
    short8v wreg[32];
    {
      const int n = g * 1024 + j0 + lm;
      const ushort* wb = (kh ? whh1 : wih1) + (size_t)n * 1024 + lq * 8;
      #pragma unroll
      for (int ks = 0; ks < 32; ++ks) wreg[ks] = *(const short8v*)(wb + ks * 32);
    }
    if (tid < 256) {
      #pragma unroll
      for (int gg = 0; gg < 4; ++gg)
        br[gg] = bih1[gg * 1024 + jf] + bhh1[gg * 1024 + jf];
    }
    float ksr = 0.f;
    for (int t = 0; t < T_; ++t) {
      // wave 0 waits h0(t) [= flag0 slot t+1]; wave 1 waits h1(t-1)
      if (w == 0) waitflags64(flag0 + (size_t)(t + 1) * 64, l);
      if (w == 1 && t > 0) waitflags64(flag1 + (size_t)(t - 1) * 64, l);
      __syncthreads();
      const ushort* h0n = HP + (size_t)(t + 1) * 16384;
      const ushort* h1p = (t > 0) ? (H1B + (size_t)(t - 1) * 16384) : ZP;
      #pragma unroll
      for (int it = 0; it < 8; ++it) {
        int g1k = w * 8 + it;             // 0..63
        int kc = g1k * 4 + lq;            // 0..255
        int m = lm ^ (kc & 15);
        const ushort* src = (kc < 128)
          ? (h0n + (size_t)m * 1024 + kc * 8)
          : (h1p + (size_t)m * 1024 + (kc - 128) * 8);
        glds16(src, Ah + g1k * 1024);
      }
      __syncthreads();
      {
        f32x4 a0 = {0.f,0.f,0.f,0.f}, a1 = {0.f,0.f,0.f,0.f};
        #pragma unroll
        for (int ks = 0; ks < 32; ks += 2) {
          int kc0 = kh * 128 + ks * 4 + lq;
          int kc1 = kc0 + 4;
          short8v f0 = *(const short8v*)(Ah + kc0 * 256 + ((lm ^ (kc0 & 15)) << 4));
          short8v f1 = *(const short8v*)(Ah + kc1 * 256 + ((lm ^ (kc1 & 15)) << 4));
          a0 = __builtin_amdgcn_mfma_f32_16x16x32_bf16(f0, wreg[ks],     a0, 0, 0, 0);
          a1 = __builtin_amdgcn_mfma_f32_16x16x32_bf16(f1, wreg[ks + 1], a1, 0, 0, 0);
        }
        #pragma unroll
        for (int q = 0; q < 4; ++q) zs[w][lq * 4 + q][lm] = a0[q] + a1[q];
      }
      __syncthreads();
      if (tid < 256) {
        float zi = zs[0][eb][ej] + zs[4][eb][ej] + br[0];
        float zf = zs[1][eb][ej] + zs[5][eb][ej] + br[1];
        float zg = zs[2][eb][ej] + zs[6][eb][ej] + br[2];
        float zo = zs[3][eb][ej] + zs[7][eb][ej] + br[3];
        float cp = sigm(zf) * creg + sigm(zi) * tanhf(zg);
        creg = cp;
        float hv = sigm(zo) * tanhf(cp);
        ksr += hv;
        __hip_atomic_store(H1B + (size_t)t * 16384 + eb * 1024 + jf, f2b(hv),
                           __ATOMIC_RELAXED, __HIP_MEMORY_SCOPE_AGENT);
        if ((t & 15) == 15) {
          KSUM[((size_t)(t >> 4) * 16 + eb) * 1024 + jf] = ksr;   // post-kernel consumer
          ksr = 0.f;
        }
      }
      __syncthreads();
      if (tid == 0)
        __hip_atomic_store(flag1 + (size_t)t * 64 + jb, 1,
                           __ATOMIC_RELEASE, __HIP_MEMORY_SCOPE_AGENT);
    }
  }
}

// gather segment-final h1 rows (bf16) into VINB [S*B, H]
__global__ __launch_bounds__(256)
void vgather(const ushort* __restrict__ H1B, ushort* __restrict__ VINB)
{
  int i = blockIdx.x * 256 + threadIdx.x;
  int row = i >> 8, c4 = (i & 255) * 4;
  int src = (row >> 4) * 256 + 240 + (row & 15);
  *(ushort4*)(VINB + (size_t)row * 1024 + c4) =
      *(const ushort4*)(H1B + (size_t)src * 1024 + c4);
}

// per-(b,t) masked softmax attention over cached segments (all f32)
__global__ __launch_bounds__(256)
void attn_kernel(const float* __restrict__ Q, const float* __restrict__ kbank,
                 const float* __restrict__ vbank, float* __restrict__ R)
{
  int row = blockIdx.x;          // t*16 + b
  int t = row >> 4, b = row & 15;
  int si = t >> 4;
  int tid = threadIdx.x, lane = tid & 63, w = tid >> 6;
  if (si == 0) {
    float4 z = {0.f, 0.f, 0.f, 0.f};
    ((float4*)(R + (size_t)row * 1024))[tid] = z;
    return;
  }
  __shared__ float sc[16];
  const float* q = Q + (size_t)row * 1024;
  for (int s = w; s < si; s += 4) {
    const float* kk = kbank + ((size_t)s * 16 + b) * 1024;
    float p = 0.f;
    for (int k = lane; k < 1024; k += 64) p += q[k] * kk[k];
    #pragma unroll
    for (int off = 32; off; off >>= 1) p += __shfl_down(p, off);
    if (lane == 0) sc[s] = p * SCALE_;
  }
  __syncthreads();
  float mx = -1e30f;
  for (int s = 0; s < si; ++s) mx = fmaxf(mx, sc[s]);
  float den = 0.f;
  for (int s = 0; s < si; ++s) den += expf(sc[s] - mx);
  float inv = 1.f / den;
  float4 accv = {0.f, 0.f, 0.f, 0.f};
  for (int s = 0; s < si; ++s) {
    float a = expf(sc[s] - mx) * inv;
    float4 vv = ((const float4*)(vbank + ((size_t)s * 16 + b) * 1024))[tid];
    accv.x += a * vv.x; accv.y += a * vv.y; accv.z += a * vv.z; accv.w += a * vv.w;
  }
  ((float4*)(R + (size_t)row * 1024))[tid] = accv;
}

// GI = [h1, R, h1-R] bf16, K=3072
__global__ __launch_bounds__(256)
void build_gi(const ushort* __restrict__ H1B, const float* __restrict__ R,
              ushort* __restrict__ GI)
{
  size_t r = blockIdx.x;
  int c4 = threadIdx.x * 4;
  ushort4 h4 = *(const ushort4*)(H1B + r * 1024 + c4);
  float4 rv = *(const float4*)(R + r * 1024 + c4);
  *(ushort4*)(GI + r * 3072 + c4) = h4;
  ushort4 rb; rb.x = f2b(rv.x); rb.y = f2b(rv.y); rb.z = f2b(rv.z); rb.w = f2b(rv.w);
  *(ushort4*)(GI + r * 3072 + 1024 + c4) = rb;
  ushort4 d;
  d.x = f2b(b2f(h4.x) - rv.x); d.y = f2b(b2f(h4.y) - rv.y);
  d.z = f2b(b2f(h4.z) - rv.z); d.w = f2b(b2f(h4.w) - rv.w);
  *(ushort4*)(GI + r * 3072 + 2048 + c4) = d;
}

// mix = gate*h1 + (1-gate)*R  -> bf16
__global__ __launch_bounds__(256)
void build_mix(const float* __restrict__ G, const ushort* __restrict__ H1B,
               const float* __restrict__ R, ushort* __restrict__ M)
{
  size_t r = blockIdx.x;
  int c4 = threadIdx.x * 4;
  float4 g = *(const float4*)(G + r * 1024 + c4);
  ushort4 h = *(const ushort4*)(H1B + r * 1024 + c4);
  float4 rv = *(const float4*)(R + r * 1024 + c4);
  ushort4 o;
  o.x = f2b(g.x * b2f(h.x) + (1.f - g.x) * rv.x);
  o.y = f2b(g.y * b2f(h.y) + (1.f - g.y) * rv.y);
  o.z = f2b(g.z * b2f(h.z) + (1.f - g.z) * rv.z);
  o.w = f2b(g.w * b2f(h.w) + (1.f - g.w) * rv.w);
  *(ushort4*)(M + r * 1024 + c4) = o;
}

// CAT = [h1, (t>=16 ? out : 0)] bf16, K=2048
__global__ __launch_bounds__(256)
void build_cat(const ushort* __restrict__ H1B, const float* __restrict__ O,
               ushort* __restrict__ C)
{
  size_t r = blockIdx.x;
  int c4 = threadIdx.x * 4;
  *(ushort4*)(C + r * 2048 + c4) = *(const ushort4*)(H1B + r * 1024 + c4);
  ushort4 o;
  if (r >= 256) {
    float4 v = *(const float4*)(O + r * 1024 + c4);
    o.x = f2b(v.x); o.y = f2b(v.y); o.z = f2b(v.z); o.w = f2b(v.w);
  } else { o.x = o.y = o.z = o.w = 0; }
  *(ushort4*)(C + r * 2048 + 1024 + c4) = o;
}

extern "C" void kernel_launch(void* const* d_in, const int* in_sizes, int n_in,
                              void* d_out, int out_size, void* d_ws, size_t ws_size,
                              hipStream_t stream) {
  const float* x     = (const float*)d_in[0];
  const float* W_ip  = (const float*)d_in[1];
  const float* b_ip  = (const float*)d_in[2];
  const float* g_ip  = (const float*)d_in[3];
  const float* be_ip = (const float*)d_in[4];
  const float* W_ih0 = (const float*)d_in[5];
  const float* W_hh0 = (const float*)d_in[6];
  const float* b_ih0 = (const float*)d_in[7];
  const float* b_hh0 = (const float*)d_in[8];
  const float* W_ih1 = (const float*)d_in[9];
  const float* W_hh1 = (const float*)d_in[10];
  const float* b_ih1 = (const float*)d_in[11];
  const float* b_hh1 = (const float*)d_in[12];
  const float* Wq    = (const float*)d_in[13];
  const float* Wk    = (const float*)d_in[14];
  const float* Wv    = (const float*)d_in[15];
  const float* Wg1   = (const float*)d_in[16];
  const float* bg1   = (const float*)d_in[17];
  const float* Wg2   = (const float*)d_in[18];
  const float* bg2   = (const float*)d_in[19];
  const float* Wo    = (const float*)d_in[20];
  const float* bo    = (const float*)d_in[21];
  const float* Wf    = (const float*)d_in[22];
  const float* bff   = (const float*)d_in[23];
  const float* g_f   = (const float*)d_in[24];
  const float* be_f  = (const float*)d_in[25];
  float* out = (float*)d_out;
  char* ws = (char*)d_ws;
  const size_t MB = (size_t)1 << 20;
  const size_t KB = (size_t)1 << 10;

  // bf16 weight pool (offsets in elements)
  ushort* WB = (ushort*)(ws);
  ushort* wipB  = WB;             // 1M
  ushort* wih0B = WB + 1*1048576; // 4M
  ushort* whh0B = WB + 5*1048576;
  ushort* wih1B = WB + 9*1048576;
  ushort* whh1B = WB + 13*1048576;
  ushort* wqB   = WB + 17*1048576;
  ushort* wkB   = WB + 18*1048576;
  ushort* wvB   = WB + 19*1048576;
  ushort* wg1B  = WB + 20*1048576; // 3M
  ushort* wg2B  = WB + 23*1048576;
  ushort* woB   = WB + 24*1048576;
  ushort* wfB   = WB + 25*1048576; // 2M -> ends 27M elems = 54MB

  ushort* XB   = (ushort*)(ws + 54 * MB);   // 8MB: x bf16, later XPB
  float*  XP   = (float*)(ws + 62 * MB);    // 16MB: input_proj pre-LN, later Q
  float*  Qf   = XP;
  char*   SCR  = ws + 78 * MB;              // 48MB scratch region
  ushort* Z0T  = (ushort*)SCR;              // 32MB bf16 [T*B,4096]
  ushort* GIB  = (ushort*)SCR;              // 24MB (after loop)
  ushort* G1B  = (ushort*)(SCR + 24 * MB);  // 8MB
  float*  GT   = (float*)(SCR + 32 * MB);   // 16MB
  ushort* MIXB = (ushort*)SCR;              // 8MB
  float*  OUTB = (float*)(SCR + 8 * MB);    // 16MB
  ushort* CATB = (ushort*)(SCR + 24 * MB);  // 16MB
  float*  FB   = (float*)SCR;               // 16MB
  ushort* H1B  = (ushort*)(ws + 126 * MB);  // 8MB
  // HP lives in the R region during phase C (R is written only afterwards)
  ushort* HP   = (ushort*)(ws + 134 * MB);  // 257*32KB = 8.22MB
  float*  R    = (float*)(ws + 134 * MB);   // 16MB (after phase C)
  char*   ST   = ws + 150 * MB;
  int*    flag0 = (int*)(ST);                     // [257][64] = 65.8KB
  int*    flag1 = (int*)(ST + 68 * KB);           // [256][64] = 64KB
  const ushort* ZPc = (const ushort*)(ST + 132 * KB);   // 32KB zeros
  float*  KSUM = (float*)(ST + 192 * KB);         // 1MB
  ushort* KSB  = (ushort*)(ST + 1216 * KB);       // 0.5MB
  float*  KBf  = (float*)(ST + 1728 * KB);        // 1MB
  float*  VBf  = (float*)(ST + 2752 * KB);        // 1MB
  ushort* VINB = (ushort*)(ST + 3776 * KB);       // 0.5MB

  // zero flags + h1(-1) zero-page; HP slot0 zeroed separately
  hipMemsetAsync(ST, 0, 164 * KB, stream);
  hipMemsetAsync(HP, 0, 32 * KB, stream);

  dim3 blk(256);
  auto cvt = [&](const float* src, ushort* dst, int n) {
    cvt_bf16<<<dim3((n / 4 + 255) / 256), blk, 0, stream>>>(src, dst, n);
  };
  // weight + input conversions
  cvt(x,     XB,    4194304);
  cvt(W_ip,  wipB,  1048576);
  cvt(W_ih0, wih0B, 4194304);
  cvt(W_hh0, whh0B, 4194304);
  cvt(W_ih1, wih1B, 4194304);
  cvt(W_hh1, whh1B, 4194304);
  cvt(Wq,    wqB,   1048576);
  cvt(Wk,    wkB,   1048576);
  cvt(Wv,    wvB,   1048576);
  cvt(Wg1,   wg1B,  3145728);
  cvt(Wg2,   wg2B,  1048576);
  cvt(Wo,    woB,   1048576);
  cvt(Wf,    wfB,   2097152);

  // Phase A: XP = x@W_ip^T + b_ip ; XPB = relu(LN(XP)) (bf16, stored in XB space)
  gemm_bf16<0,0><<<dim3(1024/128, 4096/128), blk, 0, stream>>>(
      XB, wipB, b_ip, XP, nullptr, 4096, 1024, 1024, 1.f);
  ln_relu_bf16<<<4096, blk, 0, stream>>>(XP, g_ip, be_ip, XB);
  // Phase B: Z0T = XPB@W_ih0^T + b_ih0, rows remapped to t*16+b, bf16
  gemm_bf16<0,1><<<dim3(4096/128, 4096/128), blk, 0, stream>>>(
      XB, wih0B, b_ih0, nullptr, Z0T, 4096, 4096, 1024, 1.f);
  // Phase C: single persistent cooperative kernel, all 256 steps
  {
    void* kargs[] = {
      (void*)&Z0T, (void*)&whh0B, (void*)&b_hh0,
      (void*)&wih1B, (void*)&whh1B, (void*)&b_ih1, (void*)&b_hh1,
      (void*)&HP, (void*)&H1B, (void*)&ZPc, (void*)&KSUM,
      (void*)&flag0, (void*)&flag1
    };
    hipLaunchCooperativeKernel((const void*)lstm_persistent,
                               dim3(128), dim3(512), kargs, 0, stream);
  }
  // Phase D: kbank / vbank
  cvt(KSUM, KSB, 262144);
  gemm_bf16<0,0><<<dim3(1024/128, 256/128), blk, 0, stream>>>(
      KSB, wkB, nullptr, KBf, nullptr, 256, 1024, 1024, 1.f/16.f);
  vgather<<<256, blk, 0, stream>>>(H1B, VINB);
  gemm_bf16<0,0><<<dim3(1024/128, 256/128), blk, 0, stream>>>(
      VINB, wvB, nullptr, VBf, nullptr, 256, 1024, 1024, 1.f);
  // Phase E: retrieval + gate + output
  gemm_bf16<0,0><<<dim3(1024/128, 4096/128), blk, 0, stream>>>(
      H1B, wqB, nullptr, Qf, nullptr, 4096, 1024, 1024, 1.f);
  attn_kernel<<<4096, blk, 0, stream>>>(Qf, KBf, VBf, R);
  build_gi<<<4096, blk, 0, stream>>>(H1B, R, GIB);
  gemm_bf16<1,0><<<dim3(1024/128, 4096/128), blk, 0, stream>>>(
      GIB, wg1B, bg1, nullptr, G1B, 4096, 1024, 3072, 1.f);
  gemm_bf16<2,0><<<dim3(1024/128, 4096/128), blk, 0, stream>>>(
      G1B, wg2B, bg2, GT, nullptr, 4096, 1024, 1024, 1.f);
  build_mix<<<4096, blk, 0, stream>>>(GT, H1B, R, MIXB);
  gemm_bf16<0,0><<<dim3(1024/128, 4096/128), blk, 0, stream>>>(
      MIXB, woB, bo, OUTB, nullptr, 4096, 1024, 1024, 1.f);
  build_cat<<<4096, blk, 0, stream>>>(H1B, OUTB, CATB);
  gemm_bf16<0,0><<<dim3(1024/128, 4096/128), blk, 0, stream>>>(
      CATB, wfB, bff, FB, nullptr, 4096, 1024, 2048, 1.f);
  ln_relu_final<<<4096, blk, 0, stream>>>(FB, g_f, be_f, out);
}

// Round 6
// 2331.071 us; speedup vs baseline: 1.0464x; 1.0464x over previous
//
#include <hip/hip_runtime.h>
#include <hip/hip_bf16.h>
#include <math.h>

#define B_ 16
#define T_ 256
#define D_ 1024
#define H_ 1024
#define S_ 16
#define SCALE_ (1.0f/32.0f)   // 1/sqrt(1024)

typedef __attribute__((ext_vector_type(8))) short short8v;
typedef __attribute__((ext_vector_type(4))) float f32x4;

__device__ __forceinline__ float sigm(float x) { return 1.f / (1.f + expf(-x)); }

__device__ __forceinline__ ushort f2b(float v) {
  __hip_bfloat16 h = __float2bfloat16(v);
  return *reinterpret_cast<ushort*>(&h);
}
__device__ __forceinline__ float b2f(ushort u) {
  union { unsigned u32; float f; } x; x.u32 = ((unsigned)u) << 16; return x.f;
}

__device__ __forceinline__ void glds16(const void* g, void* l) {
  __builtin_amdgcn_global_load_lds((const __attribute__((address_space(1))) void*)g,
                                   (__attribute__((address_space(3))) void*)l, 16, 0, 0);
}

// Poll 64 per-producer flag words with RELAXED agent loads (sc1 LLC reads,
// NO cache invalidate per iteration), then a single ACQUIRE fence once the
// condition holds. The fence's one-time buffer_inv makes subsequent plain
// loads (global_load_lds of h) see the producers' LLC data.
__device__ __forceinline__ void waitflags64(const int* f, int lane) {
  for (;;) {
    int v = __hip_atomic_load(f + lane, __ATOMIC_RELAXED, __HIP_MEMORY_SCOPE_AGENT);
    if (__all(v != 0)) break;
    __builtin_amdgcn_s_sleep(1);
  }
  __builtin_amdgcn_fence(__ATOMIC_ACQUIRE, "agent");
}

__device__ __forceinline__ float block_sum256(float v) {
  __shared__ float lds[4];
  #pragma unroll
  for (int off = 32; off; off >>= 1) v += __shfl_down(v, off);
  int w = threadIdx.x >> 6;
  if ((threadIdx.x & 63) == 0) lds[w] = v;
  __syncthreads();
  float r = lds[0] + lds[1] + lds[2] + lds[3];
  __syncthreads();
  return r;
}

// ---------------- fp32 -> bf16 convert ----------------
__global__ __launch_bounds__(256)
void cvt_bf16(const float* __restrict__ in, ushort* __restrict__ out, int n)
{
  int i = (blockIdx.x * 256 + threadIdx.x) * 4;
  if (i >= n) return;
  float4 v = *(const float4*)(in + i);
  ushort4 o; o.x = f2b(v.x); o.y = f2b(v.y); o.z = f2b(v.z); o.w = f2b(v.w);
  *(ushort4*)(out + i) = o;
}

// ---------------- MFMA bf16 GEMM: C = act(ascale * A@W^T + bias) ----------------
template<int ACT, int REMAP>   // ACT: 0 none, 1 relu, 2 sigmoid
__global__ __launch_bounds__(256)
void gemm_bf16(const ushort* __restrict__ A, const ushort* __restrict__ W,
               const float* __restrict__ bias,
               float* __restrict__ Cf, ushort* __restrict__ Cb,
               int M, int N, int K, float ascale)
{
  __shared__ char As[16384];
  __shared__ char Bs[16384];
  const int tid = threadIdx.x;
  const int w = tid >> 6, l = tid & 63;
  const int m0 = blockIdx.y * 128, n0 = blockIdx.x * 128;
  const int wm = w >> 1, wn = w & 1;
  const int srow = l >> 3;
  const int sbyte = ((l & 7) * 16) ^ (srow << 4);
  f32x4 acc[4][4];
  #pragma unroll
  for (int i = 0; i < 4; ++i)
    #pragma unroll
    for (int j = 0; j < 4; ++j) acc[i][j] = (f32x4){0.f, 0.f, 0.f, 0.f};

  for (int k0 = 0; k0 < K; k0 += 64) {
    __syncthreads();
    #pragma unroll
    for (int c = 0; c < 4; ++c) {
      int ca = w * 4 + c;
      int r = ca * 8 + srow;
      glds16((const char*)A + (((size_t)(m0 + r) * K + k0) << 1) + sbyte, As + ca * 1024);
      glds16((const char*)W + (((size_t)(n0 + r) * K + k0) << 1) + sbyte, Bs + ca * 1024);
    }
    __syncthreads();
    #pragma unroll
    for (int ks = 0; ks < 2; ++ks) {
      short8v a[4], b[4];
      int qb = ks * 64 + (l >> 4) * 16;
      #pragma unroll
      for (int i = 0; i < 4; ++i) {
        int ra = wm * 64 + i * 16 + (l & 15);
        a[i] = *(const short8v*)(As + ra * 128 + (qb ^ ((ra & 7) << 4)));
        int rb = wn * 64 + i * 16 + (l & 15);
        b[i] = *(const short8v*)(Bs + rb * 128 + (qb ^ ((rb & 7) << 4)));
      }
      #pragma unroll
      for (int i = 0; i < 4; ++i)
        #pragma unroll
        for (int j = 0; j < 4; ++j)
          acc[i][j] = __builtin_amdgcn_mfma_f32_16x16x32_bf16(a[i], b[j], acc[i][j], 0, 0, 0);
    }
  }
  #pragma unroll
  for (int i = 0; i < 4; ++i) {
    #pragma unroll
    for (int j = 0; j < 4; ++j) {
      int n = n0 + wn * 64 + j * 16 + (l & 15);
      float bv = bias ? bias[n] : 0.f;
      #pragma unroll
      for (int q = 0; q < 4; ++q) {
        int m = m0 + wm * 64 + i * 16 + (l >> 4) * 4 + q;
        float v = acc[i][j][q] * ascale + bv;
        if (ACT == 1) v = fmaxf(v, 0.f);
        if (ACT == 2) v = sigm(v);
        size_t off = REMAP ? ((size_t)((m & 255) * 16 + (m >> 8)) * N + n)
                           : ((size_t)m * N + n);
        if (Cf) Cf[off] = v;
        if (Cb) Cb[off] = f2b(v);
      }
    }
  }
}

// ---------------- LayerNorm+relu: f32 in -> bf16 out ----------------
__global__ __launch_bounds__(256)
void ln_relu_bf16(const float* __restrict__ X, const float* __restrict__ g,
                  const float* __restrict__ be, ushort* __restrict__ out)
{
  size_t row = blockIdx.x;
  const float4* p = (const float4*)(X + row * 1024);
  int tid = threadIdx.x;
  float4 v = p[tid];
  float s = block_sum256(v.x + v.y + v.z + v.w);
  float mean = s * (1.f / 1024.f);
  float dx = v.x - mean, dy = v.y - mean, dz = v.z - mean, dw = v.w - mean;
  float ss = block_sum256(dx*dx + dy*dy + dz*dz + dw*dw);
  float r = rsqrtf(ss * (1.f / 1024.f) + 1e-5f);
  int c4 = tid * 4;
  ushort4 o;
  o.x = f2b(fmaxf(dx * r * g[c4+0] + be[c4+0], 0.f));
  o.y = f2b(fmaxf(dy * r * g[c4+1] + be[c4+1], 0.f));
  o.z = f2b(fmaxf(dz * r * g[c4+2] + be[c4+2], 0.f));
  o.w = f2b(fmaxf(dw * r * g[c4+3] + be[c4+3], 0.f));
  *(ushort4*)(out + row * 1024 + c4) = o;
}

// final LN+relu: rows (t*B+b) f32 -> out [b][t][h] f32
__global__ __launch_bounds__(256)
void ln_relu_final(const float* __restrict__ F, const float* __restrict__ g,
                   const float* __restrict__ be, float* __restrict__ out)
{
  int row = blockIdx.x;           // t*16 + b
  int t = row >> 4, b = row & 15;
  const float4* p = (const float4*)(F + (size_t)row * 1024);
  int tid = threadIdx.x;
  float4 v = p[tid];
  float s = block_sum256(v.x + v.y + v.z + v.w);
  float mean = s * (1.f / 1024.f);
  float dx = v.x - mean, dy = v.y - mean, dz = v.z - mean, dw = v.w - mean;
  float ss = block_sum256(dx*dx + dy*dy + dz*dz + dw*dw);
  float r = rsqrtf(ss * (1.f / 1024.f) + 1e-5f);
  int c4 = tid * 4;
  float4 o;
  o.x = fmaxf(dx * r * g[c4+0] + be[c4+0], 0.f);
  o.y = fmaxf(dy * r * g[c4+1] + be[c4+1], 0.f);
  o.z = fmaxf(dz * r * g[c4+2] + be[c4+2], 0.f);
  o.w = fmaxf(dw * r * g[c4+3] + be[c4+3], 0.f);
  ((float4*)(out + ((size_t)b * T_ + t) * 1024))[tid] = o;
}

// ---------------- persistent cooperative LSTM (all 256 steps) ----------------
// 128 blocks x 512 threads, cooperative launch. Blocks 0..63: layer 0,
// blocks 64..127: layer 1; block owns 16 output cols (all 4 gates).
// Weights in VGPRs, c-state in registers. Cross-block dataflow via write-once
// per-step h buffers (relaxed agent sc1 stores -> LLC) + per-producer flag
// words. Ordering: producer = syncthreads (vmcnt drain) + ONE release fence +
// relaxed flag store; consumer = relaxed polls + ONE acquire fence on success.
// No per-poll cache invalidates.
__global__ __launch_bounds__(512)
void lstm_persistent(const ushort* __restrict__ Z0T,   // [T*B,4096] bf16
                     const ushort* __restrict__ whh0,  // [4096,1024]
                     const float* __restrict__ bhh0,
                     const ushort* __restrict__ wih1,  // [4096,1024]
                     const ushort* __restrict__ whh1,  // [4096,1024]
                     const float* __restrict__ bih1,
                     const float* __restrict__ bhh1,
                     ushort* __restrict__ HP,          // [257][16][1024], slot0 zeroed
                     ushort* __restrict__ H1B,         // [256][16][1024]
                     const ushort* __restrict__ ZP,    // 32KB zeros (h1 at t=-1)
                     float* __restrict__ KSUM,         // [S*B,1024] f32
                     int* flag0,                       // [257][64]
                     int* flag1)                       // [256][64]
{
  __shared__ char Ah[65536];
  __shared__ float zs[8][16][16];
  const int tid = threadIdx.x, w = tid >> 6, l = tid & 63;
  const int lm = l & 15, lq = l >> 4;
  const int g = w & 3, kh = w >> 2;
  const int jb = blockIdx.x & 63;
  const int j0 = jb * 16;
  const int eb = tid >> 4, ej = tid & 15, jf = j0 + ej;   // tid<256 only
  float creg = 0.f;
  float br[4];

  if (blockIdx.x < 64) {
    // ================= layer 0 =================
    short8v wreg[16];
    {
      const int n = g * 1024 + j0 + lm;
      const ushort* wb = whh0 + (size_t)n * 1024 + kh * 512 + lq * 8;
      #pragma unroll
      for (int ks = 0; ks < 16; ++ks) wreg[ks] = *(const short8v*)(wb + ks * 32);
    }
    if (tid < 256) {
      #pragma unroll
      for (int gg = 0; gg < 4; ++gg) br[gg] = bhh0[gg * 1024 + jf];
    }
    for (int t = 0; t < T_; ++t) {
      // prefetch Z0 gate pre-activations (static data) before the spin
      float z0v[4];
      if (tid < 256) {
        const ushort* zp = Z0T + ((size_t)t * 16 + eb) * 4096 + jf;
        #pragma unroll
        for (int gg = 0; gg < 4; ++gg) z0v[gg] = b2f(zp[gg * 1024]);
      }
      if (t > 0) {
        if (w == 0) waitflags64(flag0 + (size_t)t * 64, l);
        __syncthreads();
      }
      const ushort* hin = HP + (size_t)t * 16384;
      #pragma unroll
      for (int it = 0; it < 4; ++it) {
        int g1k = w * 4 + it;             // 0..31 (1KB chunks)
        int kc = g1k * 4 + lq;            // 0..127
        int m = lm ^ (kc & 15);
        glds16(hin + (size_t)m * 1024 + kc * 8, Ah + g1k * 1024);
      }
      __syncthreads();
      {
        f32x4 a0 = {0.f,0.f,0.f,0.f}, a1 = {0.f,0.f,0.f,0.f};
        #pragma unroll
        for (int ks = 0; ks < 16; ks += 2) {
          int kc0 = kh * 64 + ks * 4 + lq;
          int kc1 = kc0 + 4;
          short8v f0 = *(const short8v*)(Ah + kc0 * 256 + ((lm ^ (kc0 & 15)) << 4));
          short8v f1 = *(const short8v*)(Ah + kc1 * 256 + ((lm ^ (kc1 & 15)) << 4));
          a0 = __builtin_amdgcn_mfma_f32_16x16x32_bf16(f0, wreg[ks],     a0, 0, 0, 0);
          a1 = __builtin_amdgcn_mfma_f32_16x16x32_bf16(f1, wreg[ks + 1], a1, 0, 0, 0);
        }
        #pragma unroll
        for (int q = 0; q < 4; ++q) zs[w][lq * 4 + q][lm] = a0[q] + a1[q];
      }
      __syncthreads();
      if (tid < 256) {
        float zi = zs[0][eb][ej] + zs[4][eb][ej] + z0v[0] + br[0];
        float zf = zs[1][eb][ej] + zs[5][eb][ej] + z0v[1] + br[1];
        float zg = zs[2][eb][ej] + zs[6][eb][ej] + z0v[2] + br[2];
        float zo = zs[3][eb][ej] + zs[7][eb][ej] + z0v[3] + br[3];
        float cp = sigm(zf) * creg + sigm(zi) * tanhf(zg);
        creg = cp;
        ushort hb = f2b(sigm(zo) * tanhf(cp));
        __hip_atomic_store(HP + (size_t)(t + 1) * 16384 + eb * 1024 + jf, hb,
                           __ATOMIC_RELAXED, __HIP_MEMORY_SCOPE_AGENT);
      }
      __syncthreads();   // all waves' h stores drained (vmcnt 0)
      if (tid == 0) {
        __builtin_amdgcn_fence(__ATOMIC_RELEASE, "agent");
        __hip_atomic_store(flag0 + (size_t)(t + 1) * 64 + jb, 1,
                           __ATOMIC_RELAXED, __HIP_MEMORY_SCOPE_AGENT);
      }
    }
  } else {
    // ================= layer 1 =================
    short8v wreg[32];
    {
      const int n = g * 1024 + j0 + lm;
      const ushort* wb = (kh ? whh1 : wih1) + (size_t)n * 1024 + lq * 8;
      #pragma unroll
      for (int ks = 0; ks < 32; ++ks) wreg[ks] = *(const short8v*)(wb + ks * 32);
    }
    if (tid < 256) {
      #pragma unroll
      for (int gg = 0; gg < 4; ++gg)
        br[gg] = bih1[gg * 1024 + jf] + bhh1[gg * 1024 + jf];
    }
    float ksr = 0.f;
    for (int t = 0; t < T_; ++t) {
      // wave 0 waits h0(t) [= flag0 slot t+1]; wave 1 waits h1(t-1)
      if (w == 0) waitflags64(flag0 + (size_t)(t + 1) * 64, l);
      if (w == 1 && t > 0) waitflags64(flag1 + (size_t)(t - 1) * 64, l);
      __syncthreads();
      const ushort* h0n = HP + (size_t)(t + 1) * 16384;
      const ushort* h1p = (t > 0) ? (H1B + (size_t)(t - 1) * 16384) : ZP;
      #pragma unroll
      for (int it = 0; it < 8; ++it) {
        int g1k = w * 8 + it;             // 0..63
        int kc = g1k * 4 + lq;            // 0..255
        int m = lm ^ (kc & 15);
        const ushort* src = (kc < 128)
          ? (h0n + (size_t)m * 1024 + kc * 8)
          : (h1p + (size_t)m * 1024 + (kc - 128) * 8);
        glds16(src, Ah + g1k * 1024);
      }
      __syncthreads();
      {
        f32x4 a0 = {0.f,0.f,0.f,0.f}, a1 = {0.f,0.f,0.f,0.f};
        #pragma unroll
        for (int ks = 0; ks < 32; ks += 2) {
          int kc0 = kh * 128 + ks * 4 + lq;
          int kc1 = kc0 + 4;
          short8v f0 = *(const short8v*)(Ah + kc0 * 256 + ((lm ^ (kc0 & 15)) << 4));
          short8v f1 = *(const short8v*)(Ah + kc1 * 256 + ((lm ^ (kc1 & 15)) << 4));
          a0 = __builtin_amdgcn_mfma_f32_16x16x32_bf16(f0, wreg[ks],     a0, 0, 0, 0);
          a1 = __builtin_amdgcn_mfma_f32_16x16x32_bf16(f1, wreg[ks + 1], a1, 0, 0, 0);
        }
        #pragma unroll
        for (int q = 0; q < 4; ++q) zs[w][lq * 4 + q][lm] = a0[q] + a1[q];
      }
      __syncthreads();
      if (tid < 256) {
        float zi = zs[0][eb][ej] + zs[4][eb][ej] + br[0];
        float zf = zs[1][eb][ej] + zs[5][eb][ej] + br[1];
        float zg = zs[2][eb][ej] + zs[6][eb][ej] + br[2];
        float zo = zs[3][eb][ej] + zs[7][eb][ej] + br[3];
        float cp = sigm(zf) * creg + sigm(zi) * tanhf(zg);
        creg = cp;
        float hv = sigm(zo) * tanhf(cp);
        ksr += hv;
        __hip_atomic_store(H1B + (size_t)t * 16384 + eb * 1024 + jf, f2b(hv),
                           __ATOMIC_RELAXED, __HIP_MEMORY_SCOPE_AGENT);
        if ((t & 15) == 15) {
          KSUM[((size_t)(t >> 4) * 16 + eb) * 1024 + jf] = ksr;   // post-kernel consumer
          ksr = 0.f;
        }
      }
      __syncthreads();
      if (tid == 0) {
        __builtin_amdgcn_fence(__ATOMIC_RELEASE, "agent");
        __hip_atomic_store(flag1 + (size_t)t * 64 + jb, 1,
                           __ATOMIC_RELAXED, __HIP_MEMORY_SCOPE_AGENT);
      }
    }
  }
}

// gather segment-final h1 rows (bf16) into VINB [S*B, H]
__global__ __launch_bounds__(256)
void vgather(const ushort* __restrict__ H1B, ushort* __restrict__ VINB)
{
  int i = blockIdx.x * 256 + threadIdx.x;
  int row = i >> 8, c4 = (i & 255) * 4;
  int src = (row >> 4) * 256 + 240 + (row & 15);
  *(ushort4*)(VINB + (size_t)row * 1024 + c4) =
      *(const ushort4*)(H1B + (size_t)src * 1024 + c4);
}

// per-(b,t) masked softmax attention over cached segments (all f32)
__global__ __launch_bounds__(256)
void attn_kernel(const float* __restrict__ Q, const float* __restrict__ kbank,
                 const float* __restrict__ vbank, float* __restrict__ R)
{
  int row = blockIdx.x;          // t*16 + b
  int t = row >> 4, b = row & 15;
  int si = t >> 4;
  int tid = threadIdx.x, lane = tid & 63, w = tid >> 6;
  if (si == 0) {
    float4 z = {0.f, 0.f, 0.f, 0.f};
    ((float4*)(R + (size_t)row * 1024))[tid] = z;
    return;
  }
  __shared__ float sc[16];
  const float* q = Q + (size_t)row * 1024;
  for (int s = w; s < si; s += 4) {
    const float* kk = kbank + ((size_t)s * 16 + b) * 1024;
    float p = 0.f;
    for (int k = lane; k < 1024; k += 64) p += q[k] * kk[k];
    #pragma unroll
    for (int off = 32; off; off >>= 1) p += __shfl_down(p, off);
    if (lane == 0) sc[s] = p * SCALE_;
  }
  __syncthreads();
  float mx = -1e30f;
  for (int s = 0; s < si; ++s) mx = fmaxf(mx, sc[s]);
  float den = 0.f;
  for (int s = 0; s < si; ++s) den += expf(sc[s] - mx);
  float inv = 1.f / den;
  float4 accv = {0.f, 0.f, 0.f, 0.f};
  for (int s = 0; s < si; ++s) {
    float a = expf(sc[s] - mx) * inv;
    float4 vv = ((const float4*)(vbank + ((size_t)s * 16 + b) * 1024))[tid];
    accv.x += a * vv.x; accv.y += a * vv.y; accv.z += a * vv.z; accv.w += a * vv.w;
  }
  ((float4*)(R + (size_t)row * 1024))[tid] = accv;
}

// GI = [h1, R, h1-R] bf16, K=3072
__global__ __launch_bounds__(256)
void build_gi(const ushort* __restrict__ H1B, const float* __restrict__ R,
              ushort* __restrict__ GI)
{
  size_t r = blockIdx.x;
  int c4 = threadIdx.x * 4;
  ushort4 h4 = *(const ushort4*)(H1B + r * 1024 + c4);
  float4 rv = *(const float4*)(R + r * 1024 + c4);
  *(ushort4*)(GI + r * 3072 + c4) = h4;
  ushort4 rb; rb.x = f2b(rv.x); rb.y = f2b(rv.y); rb.z = f2b(rv.z); rb.w = f2b(rv.w);
  *(ushort4*)(GI + r * 3072 + 1024 + c4) = rb;
  ushort4 d;
  d.x = f2b(b2f(h4.x) - rv.x); d.y = f2b(b2f(h4.y) - rv.y);
  d.z = f2b(b2f(h4.z) - rv.z); d.w = f2b(b2f(h4.w) - rv.w);
  *(ushort4*)(GI + r * 3072 + 2048 + c4) = d;
}

// mix = gate*h1 + (1-gate)*R  -> bf16
__global__ __launch_bounds__(256)
void build_mix(const float* __restrict__ G, const ushort* __restrict__ H1B,
               const float* __restrict__ R, ushort* __restrict__ M)
{
  size_t r = blockIdx.x;
  int c4 = threadIdx.x * 4;
  float4 g = *(const float4*)(G + r * 1024 + c4);
  ushort4 h = *(const ushort4*)(H1B + r * 1024 + c4);
  float4 rv = *(const float4*)(R + r * 1024 + c4);
  ushort4 o;
  o.x = f2b(g.x * b2f(h.x) + (1.f - g.x) * rv.x);
  o.y = f2b(g.y * b2f(h.y) + (1.f - g.y) * rv.y);
  o.z = f2b(g.z * b2f(h.z) + (1.f - g.z) * rv.z);
  o.w = f2b(g.w * b2f(h.w) + (1.f - g.w) * rv.w);
  *(ushort4*)(M + r * 1024 + c4) = o;
}

// CAT = [h1, (t>=16 ? out : 0)] bf16, K=2048
__global__ __launch_bounds__(256)
void build_cat(const ushort* __restrict__ H1B, const float* __restrict__ O,
               ushort* __restrict__ C)
{
  size_t r = blockIdx.x;
  int c4 = threadIdx.x * 4;
  *(ushort4*)(C + r * 2048 + c4) = *(const ushort4*)(H1B + r * 1024 + c4);
  ushort4 o;
  if (r >= 256) {
    float4 v = *(const float4*)(O + r * 1024 + c4);
    o.x = f2b(v.x); o.y = f2b(v.y); o.z = f2b(v.z); o.w = f2b(v.w);
  } else { o.x = o.y = o.z = o.w = 0; }
  *(ushort4*)(C + r * 2048 + 1024 + c4) = o;
}

extern "C" void kernel_launch(void* const* d_in, const int* in_sizes, int n_in,
                              void* d_out, int out_size, void* d_ws, size_t ws_size,
                              hipStream_t stream) {
  const float* x     = (const float*)d_in[0];
  const float* W_ip  = (const float*)d_in[1];
  const float* b_ip  = (const float*)d_in[2];
  const float* g_ip  = (const float*)d_in[3];
  const float* be_ip = (const float*)d_in[4];
  const float* W_ih0 = (const float*)d_in[5];
  const float* W_hh0 = (const float*)d_in[6];
  const float* b_ih0 = (const float*)d_in[7];
  const float* b_hh0 = (const float*)d_in[8];
  const float* W_ih1 = (const float*)d_in[9];
  const float* W_hh1 = (const float*)d_in[10];
  const float* b_ih1 = (const float*)d_in[11];
  const float* b_hh1 = (const float*)d_in[12];
  const float* Wq    = (const float*)d_in[13];
  const float* Wk    = (const float*)d_in[14];
  const float* Wv    = (const float*)d_in[15];
  const float* Wg1   = (const float*)d_in[16];
  const float* bg1   = (const float*)d_in[17];
  const float* Wg2   = (const float*)d_in[18];
  const float* bg2   = (const float*)d_in[19];
  const float* Wo    = (const float*)d_in[20];
  const float* bo    = (const float*)d_in[21];
  const float* Wf    = (const float*)d_in[22];
  const float* bff   = (const float*)d_in[23];
  const float* g_f   = (const float*)d_in[24];
  const float* be_f  = (const float*)d_in[25];
  float* out = (float*)d_out;
  char* ws = (char*)d_ws;
  const size_t MB = (size_t)1 << 20;
  const size_t KB = (size_t)1 << 10;

  // bf16 weight pool (offsets in elements)
  ushort* WB = (ushort*)(ws);
  ushort* wipB  = WB;             // 1M
  ushort* wih0B = WB + 1*1048576; // 4M
  ushort* whh0B = WB + 5*1048576;
  ushort* wih1B = WB + 9*1048576;
  ushort* whh1B = WB + 13*1048576;
  ushort* wqB   = WB + 17*1048576;
  ushort* wkB   = WB + 18*1048576;
  ushort* wvB   = WB + 19*1048576;
  ushort* wg1B  = WB + 20*1048576; // 3M
  ushort* wg2B  = WB + 23*1048576;
  ushort* woB   = WB + 24*1048576;
  ushort* wfB   = WB + 25*1048576; // 2M -> ends 27M elems = 54MB

  ushort* XB   = (ushort*)(ws + 54 * MB);   // 8MB: x bf16, later XPB
  float*  XP   = (float*)(ws + 62 * MB);    // 16MB: input_proj pre-LN, later Q
  float*  Qf   = XP;
  char*   SCR  = ws + 78 * MB;              // 48MB scratch region
  ushort* Z0T  = (ushort*)SCR;              // 32MB bf16 [T*B,4096]
  ushort* GIB  = (ushort*)SCR;              // 24MB (after loop)
  ushort* G1B  = (ushort*)(SCR + 24 * MB);  // 8MB
  float*  GT   = (float*)(SCR + 32 * MB);   // 16MB
  ushort* MIXB = (ushort*)SCR;              // 8MB
  float*  OUTB = (float*)(SCR + 8 * MB);    // 16MB
  ushort* CATB = (ushort*)(SCR + 24 * MB);  // 16MB
  float*  FB   = (float*)SCR;               // 16MB
  ushort* H1B  = (ushort*)(ws + 126 * MB);  // 8MB
  // HP lives in the R region during phase C (R is written only afterwards)
  ushort* HP   = (ushort*)(ws + 134 * MB);  // 257*32KB = 8.22MB
  float*  R    = (float*)(ws + 134 * MB);   // 16MB (after phase C)
  char*   ST   = ws + 150 * MB;
  int*    flag0 = (int*)(ST);                     // [257][64] = 65.8KB
  int*    flag1 = (int*)(ST + 68 * KB);           // [256][64] = 64KB
  const ushort* ZPc = (const ushort*)(ST + 132 * KB);   // 32KB zeros
  float*  KSUM = (float*)(ST + 192 * KB);         // 1MB
  ushort* KSB  = (ushort*)(ST + 1216 * KB);       // 0.5MB
  float*  KBf  = (float*)(ST + 1728 * KB);        // 1MB
  float*  VBf  = (float*)(ST + 2752 * KB);        // 1MB
  ushort* VINB = (ushort*)(ST + 3776 * KB);       // 0.5MB

  // zero flags + h1(-1) zero-page; HP slot0 zeroed separately
  hipMemsetAsync(ST, 0, 164 * KB, stream);
  hipMemsetAsync(HP, 0, 32 * KB, stream);

  dim3 blk(256);
  auto cvt = [&](const float* src, ushort* dst, int n) {
    cvt_bf16<<<dim3((n / 4 + 255) / 256), blk, 0, stream>>>(src, dst, n);
  };
  // weight + input conversions
  cvt(x,     XB,    4194304);
  cvt(W_ip,  wipB,  1048576);
  cvt(W_ih0, wih0B, 4194304);
  cvt(W_hh0, whh0B, 4194304);
  cvt(W_ih1, wih1B, 4194304);
  cvt(W_hh1, whh1B, 4194304);
  cvt(Wq,    wqB,   1048576);
  cvt(Wk,    wkB,   1048576);
  cvt(Wv,    wvB,   1048576);
  cvt(Wg1,   wg1B,  3145728);
  cvt(Wg2,   wg2B,  1048576);
  cvt(Wo,    woB,   1048576);
  cvt(Wf,    wfB,   2097152);

  // Phase A: XP = x@W_ip^T + b_ip ; XPB = relu(LN(XP)) (bf16, stored in XB space)
  gemm_bf16<0,0><<<dim3(1024/128, 4096/128), blk, 0, stream>>>(
      XB, wipB, b_ip, XP, nullptr, 4096, 1024, 1024, 1.f);
  ln_relu_bf16<<<4096, blk, 0, stream>>>(XP, g_ip, be_ip, XB);
  // Phase B: Z0T = XPB@W_ih0^T + b_ih0, rows remapped to t*16+b, bf16
  gemm_bf16<0,1><<<dim3(4096/128, 4096/128), blk, 0, stream>>>(
      XB, wih0B, b_ih0, nullptr, Z0T, 4096, 4096, 1024, 1.f);
  // Phase C: single persistent cooperative kernel, all 256 steps
  {
    void* kargs[] = {
      (void*)&Z0T, (void*)&whh0B, (void*)&b_hh0,
      (void*)&wih1B, (void*)&whh1B, (void*)&b_ih1, (void*)&b_hh1,
      (void*)&HP, (void*)&H1B, (void*)&ZPc, (void*)&KSUM,
      (void*)&flag0, (void*)&flag1
    };
    hipLaunchCooperativeKernel((const void*)lstm_persistent,
                               dim3(128), dim3(512), kargs, 0, stream);
  }
  // Phase D: kbank / vbank
  cvt(KSUM, KSB, 262144);
  gemm_bf16<0,0><<<dim3(1024/128, 256/128), blk, 0, stream>>>(
      KSB, wkB, nullptr, KBf, nullptr, 256, 1024, 1024, 1.f/16.f);
  vgather<<<256, blk, 0, stream>>>(H1B, VINB);
  gemm_bf16<0,0><<<dim3(1024/128, 256/128), blk, 0, stream>>>(
      VINB, wvB, nullptr, VBf, nullptr, 256, 1024, 1024, 1.f);
  // Phase E: retrieval + gate + output
  gemm_bf16<0,0><<<dim3(1024/128, 4096/128), blk, 0, stream>>>(
      H1B, wqB, nullptr, Qf, nullptr, 4096, 1024, 1024, 1.f);
  attn_kernel<<<4096, blk, 0, stream>>>(Qf, KBf, VBf, R);
  build_gi<<<4096, blk, 0, stream>>>(H1B, R, GIB);
  gemm_bf16<1,0><<<dim3(1024/128, 4096/128), blk, 0, stream>>>(
      GIB, wg1B, bg1, nullptr, G1B, 4096, 1024, 3072, 1.f);
  gemm_bf16<2,0><<<dim3(1024/128, 4096/128), blk, 0, stream>>>(
      G1B, wg2B, bg2, GT, nullptr, 4096, 1024, 1024, 1.f);
  build_mix<<<4096, blk, 0, stream>>>(GT, H1B, R, MIXB);
  gemm_bf16<0,0><<<dim3(1024/128, 4096/128), blk, 0, stream>>>(
      MIXB, woB, bo, OUTB, nullptr, 4096, 1024, 1024, 1.f);
  build_cat<<<4096, blk, 0, stream>>>(H1B, OUTB, CATB);
  gemm_bf16<0,0><<<dim3(1024/128, 4096/128), blk, 0, stream>>>(
      CATB, wfB, bff, FB, nullptr, 4096, 1024, 2048, 1.f);
  ln_relu_final<<<4096, blk, 0, stream>>>(FB, g_f, be_f, out);
}

// Round 8
// 1463.905 us; speedup vs baseline: 1.6662x; 1.5924x over previous
//
#include <hip/hip_runtime.h>
#include <hip/hip_bf16.h>
#include <math.h>

#define B_ 16
#define T_ 256
#define D_ 1024
#define H_ 1024
#define S_ 16
#define SCALE_ (1.0f/32.0f)   // 1/sqrt(1024)

typedef __attribute__((ext_vector_type(8))) short short8v;
typedef __attribute__((ext_vector_type(4))) float f32x4;

__device__ __forceinline__ float sigm(float x) { return 1.f / (1.f + expf(-x)); }

__device__ __forceinline__ ushort f2b(float v) {
  __hip_bfloat16 h = __float2bfloat16(v);
  return *reinterpret_cast<ushort*>(&h);
}
__device__ __forceinline__ float b2f(ushort u) {
  union { unsigned u32; float f; } x; x.u32 = ((unsigned)u) << 16; return x.f;
}

__device__ __forceinline__ void glds16(const void* g, void* l) {
  __builtin_amdgcn_global_load_lds((const __attribute__((address_space(1))) void*)g,
                                   (__attribute__((address_space(3))) void*)l, 16, 0, 0);
}

// Poll 64 per-producer flag words with RELAXED agent loads (LLC reads, no
// cache maintenance). Data freshness needs no acquire fence: h slots are
// published via LLC-homed atomic exchanges and only ever read first-touch
// after their flag is set.
__device__ __forceinline__ void waitflags64(const int* f, int lane) {
  for (;;) {
    int v = __hip_atomic_load(f + lane, __ATOMIC_RELAXED, __HIP_MEMORY_SCOPE_AGENT);
    if (__all(v != 0)) return;
    __builtin_amdgcn_s_sleep(1);
  }
}

// publish one bf16 pair (even lanes) to a dword slot at the LLC. RMW atomics
// execute at the agent coherence point -- vmcnt ack == LLC arrival, so a
// subsequent flag store (after syncthreads' vmcnt drain) cannot overtake data.
__device__ __forceinline__ void publish_pair(ushort* base, int tid, ushort hb) {
  unsigned hi = (unsigned)__shfl_down((int)hb, 1);
  if (!(tid & 1)) {
    unsigned word = (unsigned)hb | (hi << 16);
    __hip_atomic_exchange((unsigned*)base, word,
                          __ATOMIC_RELAXED, __HIP_MEMORY_SCOPE_AGENT);
  }
}

__device__ __forceinline__ float block_sum256(float v) {
  __shared__ float lds[4];
  #pragma unroll
  for (int off = 32; off; off >>= 1) v += __shfl_down(v, off);
  int w = threadIdx.x >> 6;
  if ((threadIdx.x & 63) == 0) lds[w] = v;
  __syncthreads();
  float r = lds[0] + lds[1] + lds[2] + lds[3];
  __syncthreads();
  return r;
}

// ---------------- fp32 -> bf16 convert ----------------
__global__ __launch_bounds__(256)
void cvt_bf16(const float* __restrict__ in, ushort* __restrict__ out, int n)
{
  int i = (blockIdx.x * 256 + threadIdx.x) * 4;
  if (i >= n) return;
  float4 v = *(const float4*)(in + i);
  ushort4 o; o.x = f2b(v.x); o.y = f2b(v.y); o.z = f2b(v.z); o.w = f2b(v.w);
  *(ushort4*)(out + i) = o;
}

// ---------------- MFMA bf16 GEMM: C = act(ascale * A@W^T + bias) ----------------
template<int ACT, int REMAP>   // ACT: 0 none, 1 relu, 2 sigmoid
__global__ __launch_bounds__(256)
void gemm_bf16(const ushort* __restrict__ A, const ushort* __restrict__ W,
               const float* __restrict__ bias,
               float* __restrict__ Cf, ushort* __restrict__ Cb,
               int M, int N, int K, float ascale)
{
  __shared__ char As[16384];
  __shared__ char Bs[16384];
  const int tid = threadIdx.x;
  const int w = tid >> 6, l = tid & 63;
  const int m0 = blockIdx.y * 128, n0 = blockIdx.x * 128;
  const int wm = w >> 1, wn = w & 1;
  const int srow = l >> 3;
  const int sbyte = ((l & 7) * 16) ^ (srow << 4);
  f32x4 acc[4][4];
  #pragma unroll
  for (int i = 0; i < 4; ++i)
    #pragma unroll
    for (int j = 0; j < 4; ++j) acc[i][j] = (f32x4){0.f, 0.f, 0.f, 0.f};

  for (int k0 = 0; k0 < K; k0 += 64) {
    __syncthreads();
    #pragma unroll
    for (int c = 0; c < 4; ++c) {
      int ca = w * 4 + c;
      int r = ca * 8 + srow;
      glds16((const char*)A + (((size_t)(m0 + r) * K + k0) << 1) + sbyte, As + ca * 1024);
      glds16((const char*)W + (((size_t)(n0 + r) * K + k0) << 1) + sbyte, Bs + ca * 1024);
    }
    __syncthreads();
    #pragma unroll
    for (int ks = 0; ks < 2; ++ks) {
      short8v a[4], b[4];
      int qb = ks * 64 + (l >> 4) * 16;
      #pragma unroll
      for (int i = 0; i < 4; ++i) {
        int ra = wm * 64 + i * 16 + (l & 15);
        a[i] = *(const short8v*)(As + ra * 128 + (qb ^ ((ra & 7) << 4)));
        int rb = wn * 64 + i * 16 + (l & 15);
        b[i] = *(const short8v*)(Bs + rb * 128 + (qb ^ ((rb & 7) << 4)));
      }
      #pragma unroll
      for (int i = 0; i < 4; ++i)
        #pragma unroll
        for (int j = 0; j < 4; ++j)
          acc[i][j] = __builtin_amdgcn_mfma_f32_16x16x32_bf16(a[i], b[j], acc[i][j], 0, 0, 0);
    }
  }
  #pragma unroll
  for (int i = 0; i < 4; ++i) {
    #pragma unroll
    for (int j = 0; j < 4; ++j) {
      int n = n0 + wn * 64 + j * 16 + (l & 15);
      float bv = bias ? bias[n] : 0.f;
      #pragma unroll
      for (int q = 0; q < 4; ++q) {
        int m = m0 + wm * 64 + i * 16 + (l >> 4) * 4 + q;
        float v = acc[i][j][q] * ascale + bv;
        if (ACT == 1) v = fmaxf(v, 0.f);
        if (ACT == 2) v = sigm(v);
        size_t off = REMAP ? ((size_t)((m & 255) * 16 + (m >> 8)) * N + n)
                           : ((size_t)m * N + n);
        if (Cf) Cf[off] = v;
        if (Cb) Cb[off] = f2b(v);
      }
    }
  }
}

// ---------------- LayerNorm+relu: f32 in -> bf16 out ----------------
__global__ __launch_bounds__(256)
void ln_relu_bf16(const float* __restrict__ X, const float* __restrict__ g,
                  const float* __restrict__ be, ushort* __restrict__ out)
{
  size_t row = blockIdx.x;
  const float4* p = (const float4*)(X + row * 1024);
  int tid = threadIdx.x;
  float4 v = p[tid];
  float s = block_sum256(v.x + v.y + v.z + v.w);
  float mean = s * (1.f / 1024.f);
  float dx = v.x - mean, dy = v.y - mean, dz = v.z - mean, dw = v.w - mean;
  float ss = block_sum256(dx*dx + dy*dy + dz*dz + dw*dw);
  float r = rsqrtf(ss * (1.f / 1024.f) + 1e-5f);
  int c4 = tid * 4;
  ushort4 o;
  o.x = f2b(fmaxf(dx * r * g[c4+0] + be[c4+0], 0.f));
  o.y = f2b(fmaxf(dy * r * g[c4+1] + be[c4+1], 0.f));
  o.z = f2b(fmaxf(dz * r * g[c4+2] + be[c4+2], 0.f));
  o.w = f2b(fmaxf(dw * r * g[c4+3] + be[c4+3], 0.f));
  *(ushort4*)(out + row * 1024 + c4) = o;
}

// final LN+relu: rows (t*B+b) f32 -> out [b][t][h] f32
__global__ __launch_bounds__(256)
void ln_relu_final(const float* __restrict__ F, const float* __restrict__ g,
                   const float* __restrict__ be, float* __restrict__ out)
{
  int row = blockIdx.x;           // t*16 + b
  int t = row >> 4, b = row & 15;
  const float4* p = (const float4*)(F + (size_t)row * 1024);
  int tid = threadIdx.x;
  float4 v = p[tid];
  float s = block_sum256(v.x + v.y + v.z + v.w);
  float mean = s * (1.f / 1024.f);
  float dx = v.x - mean, dy = v.y - mean, dz = v.z - mean, dw = v.w - mean;
  float ss = block_sum256(dx*dx + dy*dy + dz*dz + dw*dw);
  float r = rsqrtf(ss * (1.f / 1024.f) + 1e-5f);
  int c4 = tid * 4;
  float4 o;
  o.x = fmaxf(dx * r * g[c4+0] + be[c4+0], 0.f);
  o.y = fmaxf(dy * r * g[c4+1] + be[c4+1], 0.f);
  o.z = fmaxf(dz * r * g[c4+2] + be[c4+2], 0.f);
  o.w = fmaxf(dw * r * g[c4+3] + be[c4+3], 0.f);
  ((float4*)(out + ((size_t)b * T_ + t) * 1024))[tid] = o;
}

// ---------------- persistent cooperative LSTM (all 256 steps) ----------------
// 128 blocks x 512 threads, cooperative launch. Blocks 0..63: layer 0,
// blocks 64..127: layer 1; block owns 16 output cols (all 4 gates).
// Weights in VGPRs, c-state in registers. Cross-block dataflow: h published
// via LLC-homed atomic exchanges (dword), then syncthreads (vmcnt drain ==
// LLC completion), then relaxed flag store. Consumers: relaxed flag polls +
// plain first-touch reads. Zero per-step cache maintenance.
__global__ __launch_bounds__(512)
void lstm_persistent(const ushort* __restrict__ Z0T,   // [T*B,4096] bf16
                     const ushort* __restrict__ whh0,  // [4096,1024]
                     const float* __restrict__ bhh0,
                     const ushort* __restrict__ wih1,  // [4096,1024]
                     const ushort* __restrict__ whh1,  // [4096,1024]
                     const float* __restrict__ bih1,
                     const float* __restrict__ bhh1,
                     ushort* __restrict__ HP,          // [257][16][1024], slot0 zeroed
                     ushort* __restrict__ H1B,         // [256][16][1024]
                     const ushort* __restrict__ ZP,    // 32KB zeros (h1 at t=-1)
                     float* __restrict__ KSUM,         // [S*B,1024] f32
                     int* flag0,                       // [257][64]
                     int* flag1)                       // [256][64]
{
  __shared__ char Ah[65536];
  __shared__ float zs[8][16][16];
  __builtin_amdgcn_fence(__ATOMIC_ACQUIRE, "agent");   // once: clear stale lines
  const int tid = threadIdx.x, w = tid >> 6, l = tid & 63;
  const int lm = l & 15, lq = l >> 4;
  const int g = w & 3, kh = w >> 2;
  const int jb = blockIdx.x & 63;
  const int j0 = jb * 16;
  const int eb = tid >> 4, ej = tid & 15, jf = j0 + ej;   // tid<256 only
  float creg = 0.f;
  float br[4];

  if (blockIdx.x < 64) {
    // ================= layer 0 =================
    short8v wreg[16];
    {
      const int n = g * 1024 + j0 + lm;
      const ushort* wb = whh0 + (size_t)n * 1024 + kh * 512 + lq * 8;
      #pragma unroll
      for (int ks = 0; ks < 16; ++ks) wreg[ks] = *(const short8v*)(wb + ks * 32);
    }
    if (tid < 256) {
      #pragma unroll
      for (int gg = 0; gg < 4; ++gg) br[gg] = bhh0[gg * 1024 + jf];
    }
    for (int t = 0; t < T_; ++t) {
      // prefetch Z0 gate pre-activations (static data) before the spin
      float z0v[4];
      if (tid < 256) {
        const ushort* zp = Z0T + ((size_t)t * 16 + eb) * 4096 + jf;
        #pragma unroll
        for (int gg = 0; gg < 4; ++gg) z0v[gg] = b2f(zp[gg * 1024]);
      }
      if (t > 0) {
        if (w == 0) waitflags64(flag0 + (size_t)t * 64, l);
        __syncthreads();
      }
      const ushort* hin = HP + (size_t)t * 16384;
      #pragma unroll
      for (int it = 0; it < 4; ++it) {
        int g1k = w * 4 + it;             // 0..31 (1KB chunks)
        int kc = g1k * 4 + lq;            // 0..127
        int m = lm ^ (kc & 15);
        glds16(hin + (size_t)m * 1024 + kc * 8, Ah + g1k * 1024);
      }
      __syncthreads();
      {
        f32x4 a0 = {0.f,0.f,0.f,0.f}, a1 = {0.f,0.f,0.f,0.f};
        #pragma unroll
        for (int ks = 0; ks < 16; ks += 2) {
          int kc0 = kh * 64 + ks * 4 + lq;
          int kc1 = kc0 + 4;
          short8v f0 = *(const short8v*)(Ah + kc0 * 256 + ((lm ^ (kc0 & 15)) << 4));
          short8v f1 = *(const short8v*)(Ah + kc1 * 256 + ((lm ^ (kc1 & 15)) << 4));
          a0 = __builtin_amdgcn_mfma_f32_16x16x32_bf16(f0, wreg[ks],     a0, 0, 0, 0);
          a1 = __builtin_amdgcn_mfma_f32_16x16x32_bf16(f1, wreg[ks + 1], a1, 0, 0, 0);
        }
        #pragma unroll
        for (int q = 0; q < 4; ++q) zs[w][lq * 4 + q][lm] = a0[q] + a1[q];
      }
      __syncthreads();
      if (tid < 256) {
        float zi = zs[0][eb][ej] + zs[4][eb][ej] + z0v[0] + br[0];
        float zf = zs[1][eb][ej] + zs[5][eb][ej] + z0v[1] + br[1];
        float zg = zs[2][eb][ej] + zs[6][eb][ej] + z0v[2] + br[2];
        float zo = zs[3][eb][ej] + zs[7][eb][ej] + z0v[3] + br[3];
        float cp = sigm(zf) * creg + sigm(zi) * tanhf(zg);
        creg = cp;
        ushort hb = f2b(sigm(zo) * tanhf(cp));
        publish_pair(HP + (size_t)(t + 1) * 16384 + eb * 1024 + jf, tid, hb);
      }
      __syncthreads();   // vmcnt drain: atomic swaps completed AT THE LLC
      if (tid == 0)
        __hip_atomic_store(flag0 + (size_t)(t + 1) * 64 + jb, 1,
                           __ATOMIC_RELAXED, __HIP_MEMORY_SCOPE_AGENT);
    }
  } else {
    // ================= layer 1 =================
    short8v wreg[32];
    {
      const int n = g * 1024 + j0 + lm;
      const ushort* wb = (kh ? whh1 : wih1) + (size_t)n * 1024 + lq * 8;
      #pragma unroll
      for (int ks = 0; ks < 32; ++ks) wreg[ks] = *(const short8v*)(wb + ks * 32);
    }
    if (tid < 256) {
      #pragma unroll
      for (int gg = 0; gg < 4; ++gg)
        br[gg] = bih1[gg * 1024 + jf] + bhh1[gg * 1024 + jf];
    }
    float ksr = 0.f;
    for (int t = 0; t < T_; ++t) {
      // h0(t) is produced by the (lighter, ahead-running) L0 chain -- usually
      // already flagged. Stage it FIRST, then overlap its read latency with
      // the own-chain flag1 wait (the critical edge).
      if (w == 0) waitflags64(flag0 + (size_t)(t + 1) * 64, l);
      __syncthreads();
      const ushort* h0n = HP + (size_t)(t + 1) * 16384;
      #pragma unroll
      for (int it = 0; it < 4; ++it) {
        int g1k = w * 4 + it;             // chunks 0..31 -> kc 0..127 (h0)
        int kc = g1k * 4 + lq;
        int m = lm ^ (kc & 15);
        glds16(h0n + (size_t)m * 1024 + kc * 8, Ah + g1k * 1024);
      }
      if (w == 1 && t > 0) waitflags64(flag1 + (size_t)(t - 1) * 64, l);
      __syncthreads();   // flag1 confirmed; h0 loads drained per-wave here
      const ushort* h1p = (t > 0) ? (H1B + (size_t)(t - 1) * 16384) : ZP;
      #pragma unroll
      for (int it = 0; it < 4; ++it) {
        int g1k = 32 + w * 4 + it;        // chunks 32..63 -> kc 128..255 (h1)
        int kc = g1k * 4 + lq;
        int m = lm ^ (kc & 15);
        glds16(h1p + (size_t)m * 1024 + (kc - 128) * 8, Ah + g1k * 1024);
      }
      __syncthreads();
      {
        f32x4 a0 = {0.f,0.f,0.f,0.f}, a1 = {0.f,0.f,0.f,0.f};
        #pragma unroll
        for (int ks = 0; ks < 32; ks += 2) {
          int kc0 = kh * 128 + ks * 4 + lq;
          int kc1 = kc0 + 4;
          short8v f0 = *(const short8v*)(Ah + kc0 * 256 + ((lm ^ (kc0 & 15)) << 4));
          short8v f1 = *(const short8v*)(Ah + kc1 * 256 + ((lm ^ (kc1 & 15)) << 4));
          a0 = __builtin_amdgcn_mfma_f32_16x16x32_bf16(f0, wreg[ks],     a0, 0, 0, 0);
          a1 = __builtin_amdgcn_mfma_f32_16x16x32_bf16(f1, wreg[ks + 1], a1, 0, 0, 0);
        }
        #pragma unroll
        for (int q = 0; q < 4; ++q) zs[w][lq * 4 + q][lm] = a0[q] + a1[q];
      }
      __syncthreads();
      if (tid < 256) {
        float zi = zs[0][eb][ej] + zs[4][eb][ej] + br[0];
        float zf = zs[1][eb][ej] + zs[5][eb][ej] + br[1];
        float zg = zs[2][eb][ej] + zs[6][eb][ej] + br[2];
        float zo = zs[3][eb][ej] + zs[7][eb][ej] + br[3];
        float cp = sigm(zf) * creg + sigm(zi) * tanhf(zg);
        creg = cp;
        float hv = sigm(zo) * tanhf(cp);
        ksr += hv;
        publish_pair(H1B + (size_t)t * 16384 + eb * 1024 + jf, tid, f2b(hv));
        if ((t & 15) == 15) {
          KSUM[((size_t)(t >> 4) * 16 + eb) * 1024 + jf] = ksr;   // post-kernel consumer
          ksr = 0.f;
        }
      }
      __syncthreads();   // vmcnt drain: swaps completed at LLC
      if (tid == 0)
        __hip_atomic_store(flag1 + (size_t)t * 64 + jb, 1,
                           __ATOMIC_RELAXED, __HIP_MEMORY_SCOPE_AGENT);
    }
  }
}

// gather segment-final h1 rows (bf16) into VINB [S*B, H]
__global__ __launch_bounds__(256)
void vgather(const ushort* __restrict__ H1B, ushort* __restrict__ VINB)
{
  int i = blockIdx.x * 256 + threadIdx.x;
  int row = i >> 8, c4 = (i & 255) * 4;
  int src = (row >> 4) * 256 + 240 + (row & 15);
  *(ushort4*)(VINB + (size_t)row * 1024 + c4) =
      *(const ushort4*)(H1B + (size_t)src * 1024 + c4);
}

// per-(b,t) masked softmax attention over cached segments (all f32)
__global__ __launch_bounds__(256)
void attn_kernel(const float* __restrict__ Q, const float* __restrict__ kbank,
                 const float* __restrict__ vbank, float* __restrict__ R)
{
  int row = blockIdx.x;          // t*16 + b
  int t = row >> 4, b = row & 15;
  int si = t >> 4;
  int tid = threadIdx.x, lane = tid & 63, w = tid >> 6;
  if (si == 0) {
    float4 z = {0.f, 0.f, 0.f, 0.f};
    ((float4*)(R + (size_t)row * 1024))[tid] = z;
    return;
  }
  __shared__ float sc[16];
  const float* q = Q + (size_t)row * 1024;
  for (int s = w; s < si; s += 4) {
    const float* kk = kbank + ((size_t)s * 16 + b) * 1024;
    float p = 0.f;
    for (int k = lane; k < 1024; k += 64) p += q[k] * kk[k];
    #pragma unroll
    for (int off = 32; off; off >>= 1) p += __shfl_down(p, off);
    if (lane == 0) sc[s] = p * SCALE_;
  }
  __syncthreads();
  float mx = -1e30f;
  for (int s = 0; s < si; ++s) mx = fmaxf(mx, sc[s]);
  float den = 0.f;
  for (int s = 0; s < si; ++s) den += expf(sc[s] - mx);
  float inv = 1.f / den;
  float4 accv = {0.f, 0.f, 0.f, 0.f};
  for (int s = 0; s < si; ++s) {
    float a = expf(sc[s] - mx) * inv;
    float4 vv = ((const float4*)(vbank + ((size_t)s * 16 + b) * 1024))[tid];
    accv.x += a * vv.x; accv.y += a * vv.y; accv.z += a * vv.z; accv.w += a * vv.w;
  }
  ((float4*)(R + (size_t)row * 1024))[tid] = accv;
}

// GI = [h1, R, h1-R] bf16, K=3072
__global__ __launch_bounds__(256)
void build_gi(const ushort* __restrict__ H1B, const float* __restrict__ R,
              ushort* __restrict__ GI)
{
  size_t r = blockIdx.x;
  int c4 = threadIdx.x * 4;
  ushort4 h4 = *(const ushort4*)(H1B + r * 1024 + c4);
  float4 rv = *(const float4*)(R + r * 1024 + c4);
  *(ushort4*)(GI + r * 3072 + c4) = h4;
  ushort4 rb; rb.x = f2b(rv.x); rb.y = f2b(rv.y); rb.z = f2b(rv.z); rb.w = f2b(rv.w);
  *(ushort4*)(GI + r * 3072 + 1024 + c4) = rb;
  ushort4 d;
  d.x = f2b(b2f(h4.x) - rv.x); d.y = f2b(b2f(h4.y) - rv.y);
  d.z = f2b(b2f(h4.z) - rv.z); d.w = f2b(b2f(h4.w) - rv.w);
  *(ushort4*)(GI + r * 3072 + 2048 + c4) = d;
}

// mix = gate*h1 + (1-gate)*R  -> bf16
__global__ __launch_bounds__(256)
void build_mix(const float* __restrict__ G, const ushort* __restrict__ H1B,
               const float* __restrict__ R, ushort* __restrict__ M)
{
  size_t r = blockIdx.x;
  int c4 = threadIdx.x * 4;
  float4 g = *(const float4*)(G + r * 1024 + c4);
  ushort4 h = *(const ushort4*)(H1B + r * 1024 + c4);
  float4 rv = *(const float4*)(R + r * 1024 + c4);
  ushort4 o;
  o.x = f2b(g.x * b2f(h.x) + (1.f - g.x) * rv.x);
  o.y = f2b(g.y * b2f(h.y) + (1.f - g.y) * rv.y);
  o.z = f2b(g.z * b2f(h.z) + (1.f - g.z) * rv.z);
  o.w = f2b(g.w * b2f(h.w) + (1.f - g.w) * rv.w);
  *(ushort4*)(M + r * 1024 + c4) = o;
}

// CAT = [h1, (t>=16 ? out : 0)] bf16, K=2048
__global__ __launch_bounds__(256)
void build_cat(const ushort* __restrict__ H1B, const float* __restrict__ O,
               ushort* __restrict__ C)
{
  size_t r = blockIdx.x;
  int c4 = threadIdx.x * 4;
  *(ushort4*)(C + r * 2048 + c4) = *(const ushort4*)(H1B + r * 1024 + c4);
  ushort4 o;
  if (r >= 256) {
    float4 v = *(const float4*)(O + r * 1024 + c4);
    o.x = f2b(v.x); o.y = f2b(v.y); o.z = f2b(v.z); o.w = f2b(v.w);
  } else { o.x = o.y = o.z = o.w = 0; }
  *(ushort4*)(C + r * 2048 + 1024 + c4) = o;
}

extern "C" void kernel_launch(void* const* d_in, const int* in_sizes, int n_in,
                              void* d_out, int out_size, void* d_ws, size_t ws_size,
                              hipStream_t stream) {
  const float* x     = (const float*)d_in[0];
  const float* W_ip  = (const float*)d_in[1];
  const float* b_ip  = (const float*)d_in[2];
  const float* g_ip  = (const float*)d_in[3];
  const float* be_ip = (const float*)d_in[4];
  const float* W_ih0 = (const float*)d_in[5];
  const float* W_hh0 = (const float*)d_in[6];
  const float* b_ih0 = (const float*)d_in[7];
  const float* b_hh0 = (const float*)d_in[8];
  const float* W_ih1 = (const float*)d_in[9];
  const float* W_hh1 = (const float*)d_in[10];
  const float* b_ih1 = (const float*)d_in[11];
  const float* b_hh1 = (const float*)d_in[12];
  const float* Wq    = (const float*)d_in[13];
  const float* Wk    = (const float*)d_in[14];
  const float* Wv    = (const float*)d_in[15];
  const float* Wg1   = (const float*)d_in[16];
  const float* bg1   = (const float*)d_in[17];
  const float* Wg2   = (const float*)d_in[18];
  const float* bg2   = (const float*)d_in[19];
  const float* Wo    = (const float*)d_in[20];
  const float* bo    = (const float*)d_in[21];
  const float* Wf    = (const float*)d_in[22];
  const float* bff   = (const float*)d_in[23];
  const float* g_f   = (const float*)d_in[24];
  const float* be_f  = (const float*)d_in[25];
  float* out = (float*)d_out;
  char* ws = (char*)d_ws;
  const size_t MB = (size_t)1 << 20;
  const size_t KB = (size_t)1 << 10;

  // bf16 weight pool (offsets in elements)
  ushort* WB = (ushort*)(ws);
  ushort* wipB  = WB;             // 1M
  ushort* wih0B = WB + 1*1048576; // 4M
  ushort* whh0B = WB + 5*1048576;
  ushort* wih1B = WB + 9*1048576;
  ushort* whh1B = WB + 13*1048576;
  ushort* wqB   = WB + 17*1048576;
  ushort* wkB   = WB + 18*1048576;
  ushort* wvB   = WB + 19*1048576;
  ushort* wg1B  = WB + 20*1048576; // 3M
  ushort* wg2B  = WB + 23*1048576;
  ushort* woB   = WB + 24*1048576;
  ushort* wfB   = WB + 25*1048576; // 2M -> ends 27M elems = 54MB

  ushort* XB   = (ushort*)(ws + 54 * MB);   // 8MB: x bf16, later XPB
  float*  XP   = (float*)(ws + 62 * MB);    // 16MB: input_proj pre-LN, later Q
  float*  Qf   = XP;
  char*   SCR  = ws + 78 * MB;              // 48MB scratch region
  ushort* Z0T  = (ushort*)SCR;              // 32MB bf16 [T*B,4096]
  ushort* GIB  = (ushort*)SCR;              // 24MB (after loop)
  ushort* G1B  = (ushort*)(SCR + 24 * MB);  // 8MB
  float*  GT   = (float*)(SCR + 32 * MB);   // 16MB
  ushort* MIXB = (ushort*)SCR;              // 8MB
  float*  OUTB = (float*)(SCR + 8 * MB);    // 16MB
  ushort* CATB = (ushort*)(SCR + 24 * MB);  // 16MB
  float*  FB   = (float*)SCR;               // 16MB
  ushort* H1B  = (ushort*)(ws + 126 * MB);  // 8MB
  // HP lives in the R region during phase C (R is written only afterwards)
  ushort* HP   = (ushort*)(ws + 134 * MB);  // 257*32KB = 8.22MB
  float*  R    = (float*)(ws + 134 * MB);   // 16MB (after phase C)
  char*   ST   = ws + 150 * MB;
  int*    flag0 = (int*)(ST);                     // [257][64] = 65.8KB
  int*    flag1 = (int*)(ST + 68 * KB);           // [256][64] = 64KB
  const ushort* ZPc = (const ushort*)(ST + 132 * KB);   // 32KB zeros
  float*  KSUM = (float*)(ST + 192 * KB);         // 1MB
  ushort* KSB  = (ushort*)(ST + 1216 * KB);       // 0.5MB
  float*  KBf  = (float*)(ST + 1728 * KB);        // 1MB
  float*  VBf  = (float*)(ST + 2752 * KB);        // 1MB
  ushort* VINB = (ushort*)(ST + 3776 * KB);       // 0.5MB

  // zero flags + h1(-1) zero-page; HP slot0 zeroed separately
  hipMemsetAsync(ST, 0, 164 * KB, stream);
  hipMemsetAsync(HP, 0, 32 * KB, stream);

  dim3 blk(256);
  auto cvt = [&](const float* src, ushort* dst, int n) {
    cvt_bf16<<<dim3((n / 4 + 255) / 256), blk, 0, stream>>>(src, dst, n);
  };
  // weight + input conversions
  cvt(x,     XB,    4194304);
  cvt(W_ip,  wipB,  1048576);
  cvt(W_ih0, wih0B, 4194304);
  cvt(W_hh0, whh0B, 4194304);
  cvt(W_ih1, wih1B, 4194304);
  cvt(W_hh1, whh1B, 4194304);
  cvt(Wq,    wqB,   1048576);
  cvt(Wk,    wkB,   1048576);
  cvt(Wv,    wvB,   1048576);
  cvt(Wg1,   wg1B,  3145728);
  cvt(Wg2,   wg2B,  1048576);
  cvt(Wo,    woB,   1048576);
  cvt(Wf,    wfB,   2097152);

  // Phase A: XP = x@W_ip^T + b_ip ; XPB = relu(LN(XP)) (bf16, stored in XB space)
  gemm_bf16<0,0><<<dim3(1024/128, 4096/128), blk, 0, stream>>>(
      XB, wipB, b_ip, XP, nullptr, 4096, 1024, 1024, 1.f);
  ln_relu_bf16<<<4096, blk, 0, stream>>>(XP, g_ip, be_ip, XB);
  // Phase B: Z0T = XPB@W_ih0^T + b_ih0, rows remapped to t*16+b, bf16
  gemm_bf16<0,1><<<dim3(4096/128, 4096/128), blk, 0, stream>>>(
      XB, wih0B, b_ih0, nullptr, Z0T, 4096, 4096, 1024, 1.f);
  // Phase C: single persistent cooperative kernel, all 256 steps
  {
    void* kargs[] = {
      (void*)&Z0T, (void*)&whh0B, (void*)&b_hh0,
      (void*)&wih1B, (void*)&whh1B, (void*)&b_ih1, (void*)&b_hh1,
      (void*)&HP, (void*)&H1B, (void*)&ZPc, (void*)&KSUM,
      (void*)&flag0, (void*)&flag1
    };
    hipLaunchCooperativeKernel((const void*)lstm_persistent,
                               dim3(128), dim3(512), kargs, 0, stream);
  }
  // Phase D: kbank / vbank
  cvt(KSUM, KSB, 262144);
  gemm_bf16<0,0><<<dim3(1024/128, 256/128), blk, 0, stream>>>(
      KSB, wkB, nullptr, KBf, nullptr, 256, 1024, 1024, 1.f/16.f);
  vgather<<<256, blk, 0, stream>>>(H1B, VINB);
  gemm_bf16<0,0><<<dim3(1024/128, 256/128), blk, 0, stream>>>(
      VINB, wvB, nullptr, VBf, nullptr, 256, 1024, 1024, 1.f);
  // Phase E: retrieval + gate + output
  gemm_bf16<0,0><<<dim3(1024/128, 4096/128), blk, 0, stream>>>(
      H1B, wqB, nullptr, Qf, nullptr, 4096, 1024, 1024, 1.f);
  attn_kernel<<<4096, blk, 0, stream>>>(Qf, KBf, VBf, R);
  build_gi<<<4096, blk, 0, stream>>>(H1B, R, GIB);
  gemm_bf16<1,0><<<dim3(1024/128, 4096/128), blk, 0, stream>>>(
      GIB, wg1B, bg1, nullptr, G1B, 4096, 1024, 3072, 1.f);
  gemm_bf16<2,0><<<dim3(1024/128, 4096/128), blk, 0, stream>>>(
      G1B, wg2B, bg2, GT, nullptr, 4096, 1024, 1024, 1.f);
  build_mix<<<4096, blk, 0, stream>>>(GT, H1B, R, MIXB);
  gemm_bf16<0,0><<<dim3(1024/128, 4096/128), blk, 0, stream>>>(
      MIXB, woB, bo, OUTB, nullptr, 4096, 1024, 1024, 1.f);
  build_cat<<<4096, blk, 0, stream>>>(H1B, OUTB, CATB);
  gemm_bf16<0,0><<<dim3(1024/128, 4096/128), blk, 0, stream>>>(
      CATB, wfB, bff, FB, nullptr, 4096, 1024, 2048, 1.f);
  ln_relu_final<<<4096, blk, 0, stream>>>(FB, g_f, be_f, out);
}

// Round 10
// 1413.216 us; speedup vs baseline: 1.7260x; 1.0359x over previous
//
#include <hip/hip_runtime.h>
#include <hip/hip_bf16.h>
#include <math.h>

#define B_ 16
#define T_ 256
#define D_ 1024
#define H_ 1024
#define S_ 16
#define SCALE_ (1.0f/32.0f)   // 1/sqrt(1024)

typedef __attribute__((ext_vector_type(8))) short short8v;
typedef __attribute__((ext_vector_type(4))) float f32x4;

__device__ __forceinline__ float sigm(float x) { return 1.f / (1.f + expf(-x)); }

__device__ __forceinline__ ushort f2b(float v) {
  __hip_bfloat16 h = __float2bfloat16(v);
  return *reinterpret_cast<ushort*>(&h);
}
__device__ __forceinline__ float b2f(ushort u) {
  union { unsigned u32; float f; } x; x.u32 = ((unsigned)u) << 16; return x.f;
}

__device__ __forceinline__ void glds16(const void* g, void* l) {
  __builtin_amdgcn_global_load_lds((const __attribute__((address_space(1))) void*)g,
                                   (__attribute__((address_space(3))) void*)l, 16, 0, 0);
}

// Poll 64 per-producer flag words with RELAXED agent loads (LLC reads, no
// cache maintenance). h slots are published via LLC-homed atomic exchanges
// and only ever read first-touch after their flag is set.
__device__ __forceinline__ void waitflags64(const int* f, int lane) {
  for (;;) {
    int v = __hip_atomic_load(f + lane, __ATOMIC_RELAXED, __HIP_MEMORY_SCOPE_AGENT);
    if (__all(v != 0)) return;
    __builtin_amdgcn_s_sleep(1);
  }
}

// publish one bf16 pair (even lanes) to a dword slot at the LLC. RMW atomics
// execute at the agent coherence point -- vmcnt ack == LLC arrival, so a
// subsequent flag store (after syncthreads' vmcnt drain) cannot overtake data.
__device__ __forceinline__ void publish_pair(ushort* base, int tid, ushort hb) {
  unsigned hi = (unsigned)__shfl_down((int)hb, 1);
  if (!(tid & 1)) {
    unsigned word = (unsigned)hb | (hi << 16);
    __hip_atomic_exchange((unsigned*)base, word,
                          __ATOMIC_RELAXED, __HIP_MEMORY_SCOPE_AGENT);
  }
}

__device__ __forceinline__ float block_sum256(float v) {
  __shared__ float lds[4];
  #pragma unroll
  for (int off = 32; off; off >>= 1) v += __shfl_down(v, off);
  int w = threadIdx.x >> 6;
  if ((threadIdx.x & 63) == 0) lds[w] = v;
  __syncthreads();
  float r = lds[0] + lds[1] + lds[2] + lds[3];
  __syncthreads();
  return r;
}

// ---------------- fused fp32 -> bf16 convert (all tensors, one launch) ----
#define NJOBS 14
struct CvtJobs {
  const float* src[NJOBS];
  ushort* dst[NJOBS];
  int cum[NJOBS + 1];   // prefix sums in float4 units
};

__global__ __launch_bounds__(256)
void cvt_all(CvtJobs J)
{
  int i = blockIdx.x * 256 + threadIdx.x;
  if (i >= J.cum[NJOBS]) return;
  int j = 0;
  #pragma unroll
  for (int k = 1; k < NJOBS; ++k) j += (i >= J.cum[k]) ? 1 : 0;
  int idx = i - J.cum[j];
  float4 v = ((const float4*)J.src[j])[idx];
  ushort4 o; o.x = f2b(v.x); o.y = f2b(v.y); o.z = f2b(v.z); o.w = f2b(v.w);
  ((ushort4*)J.dst[j])[idx] = o;
}

// small single-tensor cvt (KSUM)
__global__ __launch_bounds__(256)
void cvt_bf16(const float* __restrict__ in, ushort* __restrict__ out, int n)
{
  int i = (blockIdx.x * 256 + threadIdx.x) * 4;
  if (i >= n) return;
  float4 v = *(const float4*)(in + i);
  ushort4 o; o.x = f2b(v.x); o.y = f2b(v.y); o.z = f2b(v.z); o.w = f2b(v.w);
  *(ushort4*)(out + i) = o;
}

// ---------------- MFMA bf16 GEMM: C = act(ascale * A@W^T + bias) ----------------
// ACT: 0 none, 1 relu, 2 sigmoid,
//      3 mix   (gate=sigm(v); out = gate*h1 + (1-gate)*R, bf16; Hx/Rx row = m)
//      4 masked (out = m>=256 ? v : 0; for the CAT second half)
template<int ACT, int REMAP>
__global__ __launch_bounds__(256)
void gemm_bf16(const ushort* __restrict__ A, const ushort* __restrict__ W,
               const float* __restrict__ bias,
               float* __restrict__ Cf, ushort* __restrict__ Cb,
               int M, int N, int K, float ascale, int ldc,
               const ushort* __restrict__ Hx, const float* __restrict__ Rx)
{
  __shared__ char As[16384];
  __shared__ char Bs[16384];
  const int tid = threadIdx.x;
  const int w = tid >> 6, l = tid & 63;
  const int m0 = blockIdx.y * 128, n0 = blockIdx.x * 128;
  const int wm = w >> 1, wn = w & 1;
  const int srow = l >> 3;
  const int sbyte = ((l & 7) * 16) ^ (srow << 4);
  f32x4 acc[4][4];
  #pragma unroll
  for (int i = 0; i < 4; ++i)
    #pragma unroll
    for (int j = 0; j < 4; ++j) acc[i][j] = (f32x4){0.f, 0.f, 0.f, 0.f};

  for (int k0 = 0; k0 < K; k0 += 64) {
    __syncthreads();
    #pragma unroll
    for (int c = 0; c < 4; ++c) {
      int ca = w * 4 + c;
      int r = ca * 8 + srow;
      glds16((const char*)A + (((size_t)(m0 + r) * K + k0) << 1) + sbyte, As + ca * 1024);
      glds16((const char*)W + (((size_t)(n0 + r) * K + k0) << 1) + sbyte, Bs + ca * 1024);
    }
    __syncthreads();
    #pragma unroll
    for (int ks = 0; ks < 2; ++ks) {
      short8v a[4], b[4];
      int qb = ks * 64 + (l >> 4) * 16;
      #pragma unroll
      for (int i = 0; i < 4; ++i) {
        int ra = wm * 64 + i * 16 + (l & 15);
        a[i] = *(const short8v*)(As + ra * 128 + (qb ^ ((ra & 7) << 4)));
        int rb = wn * 64 + i * 16 + (l & 15);
        b[i] = *(const short8v*)(Bs + rb * 128 + (qb ^ ((rb & 7) << 4)));
      }
      #pragma unroll
      for (int i = 0; i < 4; ++i)
        #pragma unroll
        for (int j = 0; j < 4; ++j)
          acc[i][j] = __builtin_amdgcn_mfma_f32_16x16x32_bf16(a[i], b[j], acc[i][j], 0, 0, 0);
    }
  }
  #pragma unroll
  for (int i = 0; i < 4; ++i) {
    #pragma unroll
    for (int j = 0; j < 4; ++j) {
      int n = n0 + wn * 64 + j * 16 + (l & 15);
      float bv = bias ? bias[n] : 0.f;
      #pragma unroll
      for (int q = 0; q < 4; ++q) {
        int m = m0 + wm * 64 + i * 16 + (l >> 4) * 4 + q;
        float v = acc[i][j][q] * ascale + bv;
        if (ACT == 1) v = fmaxf(v, 0.f);
        if (ACT == 2) v = sigm(v);
        if (ACT == 3) {
          float gte = sigm(v);
          float h = b2f(Hx[(size_t)m * 1024 + n]);
          float r = Rx[(size_t)m * 1024 + n];
          v = gte * h + (1.f - gte) * r;
        }
        if (ACT == 4) v = (m >= 256) ? v : 0.f;
        size_t off = REMAP ? ((size_t)((m & 255) * 16 + (m >> 8)) * ldc + n)
                           : ((size_t)m * ldc + n);
        if (Cf) Cf[off] = v;
        if (Cb) Cb[off] = f2b(v);
      }
    }
  }
}

// ---------------- LayerNorm+relu: f32 in -> bf16 out ----------------
__global__ __launch_bounds__(256)
void ln_relu_bf16(const float* __restrict__ X, const float* __restrict__ g,
                  const float* __restrict__ be, ushort* __restrict__ out)
{
  size_t row = blockIdx.x;
  const float4* p = (const float4*)(X + row * 1024);
  int tid = threadIdx.x;
  float4 v = p[tid];
  float s = block_sum256(v.x + v.y + v.z + v.w);
  float mean = s * (1.f / 1024.f);
  float dx = v.x - mean, dy = v.y - mean, dz = v.z - mean, dw = v.w - mean;
  float ss = block_sum256(dx*dx + dy*dy + dz*dz + dw*dw);
  float r = rsqrtf(ss * (1.f / 1024.f) + 1e-5f);
  int c4 = tid * 4;
  ushort4 o;
  o.x = f2b(fmaxf(dx * r * g[c4+0] + be[c4+0], 0.f));
  o.y = f2b(fmaxf(dy * r * g[c4+1] + be[c4+1], 0.f));
  o.z = f2b(fmaxf(dz * r * g[c4+2] + be[c4+2], 0.f));
  o.w = f2b(fmaxf(dw * r * g[c4+3] + be[c4+3], 0.f));
  *(ushort4*)(out + row * 1024 + c4) = o;
}

// final LN+relu: rows (t*B+b) f32 -> out [b][t][h] f32
__global__ __launch_bounds__(256)
void ln_relu_final(const float* __restrict__ F, const float* __restrict__ g,
                   const float* __restrict__ be, float* __restrict__ out)
{
  int row = blockIdx.x;           // t*16 + b
  int t = row >> 4, b = row & 15;
  const float4* p = (const float4*)(F + (size_t)row * 1024);
  int tid = threadIdx.x;
  float4 v = p[tid];
  float s = block_sum256(v.x + v.y + v.z + v.w);
  float mean = s * (1.f / 1024.f);
  float dx = v.x - mean, dy = v.y - mean, dz = v.z - mean, dw = v.w - mean;
  float ss = block_sum256(dx*dx + dy*dy + dz*dz + dw*dw);
  float r = rsqrtf(ss * (1.f / 1024.f) + 1e-5f);
  int c4 = tid * 4;
  float4 o;
  o.x = fmaxf(dx * r * g[c4+0] + be[c4+0], 0.f);
  o.y = fmaxf(dy * r * g[c4+1] + be[c4+1], 0.f);
  o.z = fmaxf(dz * r * g[c4+2] + be[c4+2], 0.f);
  o.w = fmaxf(dw * r * g[c4+3] + be[c4+3], 0.f);
  ((float4*)(out + ((size_t)b * T_ + t) * 1024))[tid] = o;
}

// ---------------- persistent cooperative LSTM (all 256 steps) ----------------
// VERBATIM the round-8 version (passed at 991us): blocks 0..63 layer 0,
// 64..127 layer 1; weights in VGPRs, c in registers. h published via
// LLC-homed atomic exchanges -> syncthreads (vmcnt drain == LLC completion)
// -> relaxed flag store. Consumers: designated-wave relaxed polls + plain
// first-touch reads. Do NOT de-serialize this (r9 lesson: the extra barriers
// are load-bearing slack for the publication window).
__global__ __launch_bounds__(512)
void lstm_persistent(const ushort* __restrict__ Z0T,   // [T*B,4096] bf16
                     const ushort* __restrict__ whh0,  // [4096,1024]
                     const float* __restrict__ bhh0,
                     const ushort* __restrict__ wih1,  // [4096,1024]
                     const ushort* __restrict__ whh1,  // [4096,1024]
                     const float* __restrict__ bih1,
                     const float* __restrict__ bhh1,
                     ushort* __restrict__ HP,          // [257][16][1024], slot0 zeroed
                     ushort* __restrict__ H1B,         // [256][16][1024]
                     const ushort* __restrict__ ZP,    // 32KB zeros (h1 at t=-1)
                     float* __restrict__ KSUM,         // [S*B,1024] f32
                     int* flag0,                       // [257][64]
                     int* flag1)                       // [256][64]
{
  __shared__ char Ah[65536];
  __shared__ float zs[8][16][16];
  __builtin_amdgcn_fence(__ATOMIC_ACQUIRE, "agent");   // once: clear stale lines
  const int tid = threadIdx.x, w = tid >> 6, l = tid & 63;
  const int lm = l & 15, lq = l >> 4;
  const int g = w & 3, kh = w >> 2;
  const int jb = blockIdx.x & 63;
  const int j0 = jb * 16;
  const int eb = tid >> 4, ej = tid & 15, jf = j0 + ej;   // tid<256 only
  float creg = 0.f;
  float br[4];

  if (blockIdx.x < 64) {
    // ================= layer 0 =================
    short8v wreg[16];
    {
      const int n = g * 1024 + j0 + lm;
      const ushort* wb = whh0 + (size_t)n * 1024 + kh * 512 + lq * 8;
      #pragma unroll
      for (int ks = 0; ks < 16; ++ks) wreg[ks] = *(const short8v*)(wb + ks * 32);
    }
    if (tid < 256) {
      #pragma unroll
      for (int gg = 0; gg < 4; ++gg) br[gg] = bhh0[gg * 1024 + jf];
    }
    for (int t = 0; t < T_; ++t) {
      // prefetch Z0 gate pre-activations (static data) before the spin
      float z0v[4];
      if (tid < 256) {
        const ushort* zp = Z0T + ((size_t)t * 16 + eb) * 4096 + jf;
        #pragma unroll
        for (int gg = 0; gg < 4; ++gg) z0v[gg] = b2f(zp[gg * 1024]);
      }
      if (t > 0) {
        if (w == 0) waitflags64(flag0 + (size_t)t * 64, l);
        __syncthreads();
      }
      const ushort* hin = HP + (size_t)t * 16384;
      #pragma unroll
      for (int it = 0; it < 4; ++it) {
        int g1k = w * 4 + it;             // 0..31 (1KB chunks)
        int kc = g1k * 4 + lq;            // 0..127
        int m = lm ^ (kc & 15);
        glds16(hin + (size_t)m * 1024 + kc * 8, Ah + g1k * 1024);
      }
      __syncthreads();
      {
        f32x4 a0 = {0.f,0.f,0.f,0.f}, a1 = {0.f,0.f,0.f,0.f};
        #pragma unroll
        for (int ks = 0; ks < 16; ks += 2) {
          int kc0 = kh * 64 + ks * 4 + lq;
          int kc1 = kc0 + 4;
          short8v f0 = *(const short8v*)(Ah + kc0 * 256 + ((lm ^ (kc0 & 15)) << 4));
          short8v f1 = *(const short8v*)(Ah + kc1 * 256 + ((lm ^ (kc1 & 15)) << 4));
          a0 = __builtin_amdgcn_mfma_f32_16x16x32_bf16(f0, wreg[ks],     a0, 0, 0, 0);
          a1 = __builtin_amdgcn_mfma_f32_16x16x32_bf16(f1, wreg[ks + 1], a1, 0, 0, 0);
        }
        #pragma unroll
        for (int q = 0; q < 4; ++q) zs[w][lq * 4 + q][lm] = a0[q] + a1[q];
      }
      __syncthreads();
      if (tid < 256) {
        float zi = zs[0][eb][ej] + zs[4][eb][ej] + z0v[0] + br[0];
        float zf = zs[1][eb][ej] + zs[5][eb][ej] + z0v[1] + br[1];
        float zg = zs[2][eb][ej] + zs[6][eb][ej] + z0v[2] + br[2];
        float zo = zs[3][eb][ej] + zs[7][eb][ej] + z0v[3] + br[3];
        float cp = sigm(zf) * creg + sigm(zi) * tanhf(zg);
        creg = cp;
        ushort hb = f2b(sigm(zo) * tanhf(cp));
        publish_pair(HP + (size_t)(t + 1) * 16384 + eb * 1024 + jf, tid, hb);
      }
      __syncthreads();   // vmcnt drain: atomic swaps completed AT THE LLC
      if (tid == 0)
        __hip_atomic_store(flag0 + (size_t)(t + 1) * 64 + jb, 1,
                           __ATOMIC_RELAXED, __HIP_MEMORY_SCOPE_AGENT);
    }
  } else {
    // ================= layer 1 =================
    short8v wreg[32];
    {
      const int n = g * 1024 + j0 + lm;
      const ushort* wb = (kh ? whh1 : wih1) + (size_t)n * 1024 + lq * 8;
      #pragma unroll
      for (int ks = 0; ks < 32; ++ks) wreg[ks] = *(const short8v*)(wb + ks * 32);
    }
    if (tid < 256) {
      #pragma unroll
      for (int gg = 0; gg < 4; ++gg)
        br[gg] = bih1[gg * 1024 + jf] + bhh1[gg * 1024 + jf];
    }
    float ksr = 0.f;
    for (int t = 0; t < T_; ++t) {
      // h0(t) is produced by the (lighter, ahead-running) L0 chain -- usually
      // already flagged. Stage it FIRST, then overlap its read latency with
      // the own-chain flag1 wait (the critical edge).
      if (w == 0) waitflags64(flag0 + (size_t)(t + 1) * 64, l);
      __syncthreads();
      const ushort* h0n = HP + (size_t)(t + 1) * 16384;
      #pragma unroll
      for (int it = 0; it < 4; ++it) {
        int g1k = w * 4 + it;             // chunks 0..31 -> kc 0..127 (h0)
        int kc = g1k * 4 + lq;
        int m = lm ^ (kc & 15);
        glds16(h0n + (size_t)m * 1024 + kc * 8, Ah + g1k * 1024);
      }
      if (w == 1 && t > 0) waitflags64(flag1 + (size_t)(t - 1) * 64, l);
      __syncthreads();   // flag1 confirmed; h0 loads drained per-wave here
      const ushort* h1p = (t > 0) ? (H1B + (size_t)(t - 1) * 16384) : ZP;
      #pragma unroll
      for (int it = 0; it < 4; ++it) {
        int g1k = 32 + w * 4 + it;        // chunks 32..63 -> kc 128..255 (h1)
        int kc = g1k * 4 + lq;
        int m = lm ^ (kc & 15);
        glds16(h1p + (size_t)m * 1024 + (kc - 128) * 8, Ah + g1k * 1024);
      }
      __syncthreads();
      {
        f32x4 a0 = {0.f,0.f,0.f,0.f}, a1 = {0.f,0.f,0.f,0.f};
        #pragma unroll
        for (int ks = 0; ks < 32; ks += 2) {
          int kc0 = kh * 128 + ks * 4 + lq;
          int kc1 = kc0 + 4;
          short8v f0 = *(const short8v*)(Ah + kc0 * 256 + ((lm ^ (kc0 & 15)) << 4));
          short8v f1 = *(const short8v*)(Ah + kc1 * 256 + ((lm ^ (kc1 & 15)) << 4));
          a0 = __builtin_amdgcn_mfma_f32_16x16x32_bf16(f0, wreg[ks],     a0, 0, 0, 0);
          a1 = __builtin_amdgcn_mfma_f32_16x16x32_bf16(f1, wreg[ks + 1], a1, 0, 0, 0);
        }
        #pragma unroll
        for (int q = 0; q < 4; ++q) zs[w][lq * 4 + q][lm] = a0[q] + a1[q];
      }
      __syncthreads();
      if (tid < 256) {
        float zi = zs[0][eb][ej] + zs[4][eb][ej] + br[0];
        float zf = zs[1][eb][ej] + zs[5][eb][ej] + br[1];
        float zg = zs[2][eb][ej] + zs[6][eb][ej] + br[2];
        float zo = zs[3][eb][ej] + zs[7][eb][ej] + br[3];
        float cp = sigm(zf) * creg + sigm(zi) * tanhf(zg);
        creg = cp;
        float hv = sigm(zo) * tanhf(cp);
        ksr += hv;
        publish_pair(H1B + (size_t)t * 16384 + eb * 1024 + jf, tid, f2b(hv));
        if ((t & 15) == 15) {
          KSUM[((size_t)(t >> 4) * 16 + eb) * 1024 + jf] = ksr;   // post-kernel consumer
          ksr = 0.f;
        }
      }
      __syncthreads();   // vmcnt drain: swaps completed at LLC
      if (tid == 0)
        __hip_atomic_store(flag1 + (size_t)t * 64 + jb, 1,
                           __ATOMIC_RELAXED, __HIP_MEMORY_SCOPE_AGENT);
    }
  }
}

// gather segment-final h1 rows (bf16) into VINB [S*B, H]
__global__ __launch_bounds__(256)
void vgather(const ushort* __restrict__ H1B, ushort* __restrict__ VINB)
{
  int i = blockIdx.x * 256 + threadIdx.x;
  int row = i >> 8, c4 = (i & 255) * 4;
  int src = (row >> 4) * 256 + 240 + (row & 15);
  *(ushort4*)(VINB + (size_t)row * 1024 + c4) =
      *(const ushort4*)(H1B + (size_t)src * 1024 + c4);
}

// per-(b,t) masked softmax attention over cached segments (all f32)
__global__ __launch_bounds__(256)
void attn_kernel(const float* __restrict__ Q, const float* __restrict__ kbank,
                 const float* __restrict__ vbank, float* __restrict__ R)
{
  int row = blockIdx.x;          // t*16 + b
  int t = row >> 4, b = row & 15;
  int si = t >> 4;
  int tid = threadIdx.x, lane = tid & 63, w = tid >> 6;
  if (si == 0) {
    float4 z = {0.f, 0.f, 0.f, 0.f};
    ((float4*)(R + (size_t)row * 1024))[tid] = z;
    return;
  }
  __shared__ float sc[16];
  const float* q = Q + (size_t)row * 1024;
  for (int s = w; s < si; s += 4) {
    const float* kk = kbank + ((size_t)s * 16 + b) * 1024;
    float p = 0.f;
    for (int k = lane; k < 1024; k += 64) p += q[k] * kk[k];
    #pragma unroll
    for (int off = 32; off; off >>= 1) p += __shfl_down(p, off);
    if (lane == 0) sc[s] = p * SCALE_;
  }
  __syncthreads();
  float mx = -1e30f;
  for (int s = 0; s < si; ++s) mx = fmaxf(mx, sc[s]);
  float den = 0.f;
  for (int s = 0; s < si; ++s) den += expf(sc[s] - mx);
  float inv = 1.f / den;
  float4 accv = {0.f, 0.f, 0.f, 0.f};
  for (int s = 0; s < si; ++s) {
    float a = expf(sc[s] - mx) * inv;
    float4 vv = ((const float4*)(vbank + ((size_t)s * 16 + b) * 1024))[tid];
    accv.x += a * vv.x; accv.y += a * vv.y; accv.z += a * vv.z; accv.w += a * vv.w;
  }
  ((float4*)(R + (size_t)row * 1024))[tid] = accv;
}

// GI = [h1, R, h1-R] bf16 (K=3072) AND CAT first half: CATB[r*2048 + c] = h1
__global__ __launch_bounds__(256)
void build_gi_cat(const ushort* __restrict__ H1B, const float* __restrict__ R,
                  ushort* __restrict__ GI, ushort* __restrict__ CATB)
{
  size_t r = blockIdx.x;
  int c4 = threadIdx.x * 4;
  ushort4 h4 = *(const ushort4*)(H1B + r * 1024 + c4);
  float4 rv = *(const float4*)(R + r * 1024 + c4);
  *(ushort4*)(GI + r * 3072 + c4) = h4;
  ushort4 rb; rb.x = f2b(rv.x); rb.y = f2b(rv.y); rb.z = f2b(rv.z); rb.w = f2b(rv.w);
  *(ushort4*)(GI + r * 3072 + 1024 + c4) = rb;
  ushort4 d;
  d.x = f2b(b2f(h4.x) - rv.x); d.y = f2b(b2f(h4.y) - rv.y);
  d.z = f2b(b2f(h4.z) - rv.z); d.w = f2b(b2f(h4.w) - rv.w);
  *(ushort4*)(GI + r * 3072 + 2048 + c4) = d;
  *(ushort4*)(CATB + r * 2048 + c4) = h4;
}

extern "C" void kernel_launch(void* const* d_in, const int* in_sizes, int n_in,
                              void* d_out, int out_size, void* d_ws, size_t ws_size,
                              hipStream_t stream) {
  const float* x     = (const float*)d_in[0];
  const float* W_ip  = (const float*)d_in[1];
  const float* b_ip  = (const float*)d_in[2];
  const float* g_ip  = (const float*)d_in[3];
  const float* be_ip = (const float*)d_in[4];
  const float* W_ih0 = (const float*)d_in[5];
  const float* W_hh0 = (const float*)d_in[6];
  const float* b_ih0 = (const float*)d_in[7];
  const float* b_hh0 = (const float*)d_in[8];
  const float* W_ih1 = (const float*)d_in[9];
  const float* W_hh1 = (const float*)d_in[10];
  const float* b_ih1 = (const float*)d_in[11];
  const float* b_hh1 = (const float*)d_in[12];
  const float* Wq    = (const float*)d_in[13];
  const float* Wk    = (const float*)d_in[14];
  const float* Wv    = (const float*)d_in[15];
  const float* Wg1   = (const float*)d_in[16];
  const float* bg1   = (const float*)d_in[17];
  const float* Wg2   = (const float*)d_in[18];
  const float* bg2   = (const float*)d_in[19];
  const float* Wo    = (const float*)d_in[20];
  const float* bo    = (const float*)d_in[21];
  const float* Wf    = (const float*)d_in[22];
  const float* bff   = (const float*)d_in[23];
  const float* g_f   = (const float*)d_in[24];
  const float* be_f  = (const float*)d_in[25];
  float* out = (float*)d_out;
  char* ws = (char*)d_ws;
  const size_t MB = (size_t)1 << 20;
  const size_t KB = (size_t)1 << 10;

  // bf16 weight pool (offsets in elements)
  ushort* WB = (ushort*)(ws);
  ushort* wipB  = WB;             // 1M
  ushort* wih0B = WB + 1*1048576; // 4M
  ushort* whh0B = WB + 5*1048576;
  ushort* wih1B = WB + 9*1048576;
  ushort* whh1B = WB + 13*1048576;
  ushort* wqB   = WB + 17*1048576;
  ushort* wkB   = WB + 18*1048576;
  ushort* wvB   = WB + 19*1048576;
  ushort* wg1B  = WB + 20*1048576; // 3M
  ushort* wg2B  = WB + 23*1048576;
  ushort* woB   = WB + 24*1048576;
  ushort* wfB   = WB + 25*1048576; // 2M -> ends 27M elems = 54MB

  ushort* XB   = (ushort*)(ws + 54 * MB);   // 8MB: x bf16, later XPB
  float*  XP   = (float*)(ws + 62 * MB);    // 16MB: input_proj pre-LN, later Q
  float*  Qf   = XP;
  char*   SCR  = ws + 78 * MB;              // 48MB scratch region
  ushort* Z0T  = (ushort*)SCR;              // 32MB bf16 [T*B,4096] (phase B/C)
  // post-loop overlays (Z0T dead after phase C):
  ushort* GIB  = (ushort*)SCR;              // 24MB  [4096,3072]
  ushort* CATB = (ushort*)(SCR + 24 * MB);  // 16MB  [4096,2048]
  ushort* G1B  = (ushort*)(SCR + 40 * MB);  // 8MB   [4096,1024]
  ushort* MIXB = (ushort*)SCR;              // 8MB (reuses GIB after Wg1)
  float*  FB   = (float*)SCR;               // 16MB (reuses MIXB after Wo)
  ushort* H1B  = (ushort*)(ws + 126 * MB);  // 8MB
  // HP lives in the R region during phase C (R is written only afterwards)
  ushort* HP   = (ushort*)(ws + 134 * MB);  // 257*32KB = 8.22MB
  float*  R    = (float*)(ws + 134 * MB);   // 16MB (after phase C)
  char*   ST   = ws + 150 * MB;
  int*    flag0 = (int*)(ST);                     // [257][64] = 65.8KB
  int*    flag1 = (int*)(ST + 68 * KB);           // [256][64] = 64KB
  const ushort* ZPc = (const ushort*)(ST + 132 * KB);   // 32KB zeros
  float*  KSUM = (float*)(ST + 192 * KB);         // 1MB
  ushort* KSB  = (ushort*)(ST + 1216 * KB);       // 0.5MB
  float*  KBf  = (float*)(ST + 1728 * KB);        // 1MB
  float*  VBf  = (float*)(ST + 2752 * KB);        // 1MB
  ushort* VINB = (ushort*)(ST + 3776 * KB);       // 0.5MB

  // zero flags + h1(-1) zero-page; HP slot0 zeroed separately
  hipMemsetAsync(ST, 0, 164 * KB, stream);
  hipMemsetAsync(HP, 0, 32 * KB, stream);

  dim3 blk(256);
  // fused weight + input conversion (single launch)
  {
    CvtJobs J;
    const float* srcs[NJOBS] = { x, W_ip, W_ih0, W_hh0, W_ih1, W_hh1,
                                 Wq, Wk, Wv, Wg1, Wg2, Wo, Wf, nullptr };
    ushort* dsts[NJOBS] = { XB, wipB, wih0B, whh0B, wih1B, whh1B,
                            wqB, wkB, wvB, wg1B, wg2B, woB, wfB, nullptr };
    int n4[NJOBS] = { 1048576, 262144, 1048576, 1048576, 1048576, 1048576,
                      262144, 262144, 262144, 786432, 262144, 262144,
                      524288, 0 };
    int c = 0;
    for (int j = 0; j < NJOBS; ++j) {
      J.src[j] = srcs[j] ? srcs[j] : x;
      J.dst[j] = dsts[j] ? dsts[j] : XB;
      J.cum[j] = c;
      c += n4[j];
    }
    J.cum[NJOBS] = c;                    // 8,126,464 float4 items
    cvt_all<<<dim3((c + 255) / 256), blk, 0, stream>>>(J);
  }

  // Phase A: XP = x@W_ip^T + b_ip ; XPB = relu(LN(XP)) (bf16, stored in XB)
  gemm_bf16<0,0><<<dim3(1024/128, 4096/128), blk, 0, stream>>>(
      XB, wipB, b_ip, XP, nullptr, 4096, 1024, 1024, 1.f, 1024, nullptr, nullptr);
  ln_relu_bf16<<<4096, blk, 0, stream>>>(XP, g_ip, be_ip, XB);
  // Phase B: Z0T = XPB@W_ih0^T + b_ih0, rows remapped to t*16+b, bf16
  gemm_bf16<0,1><<<dim3(4096/128, 4096/128), blk, 0, stream>>>(
      XB, wih0B, b_ih0, nullptr, Z0T, 4096, 4096, 1024, 1.f, 4096, nullptr, nullptr);
  // Phase C: single persistent cooperative kernel, all 256 steps
  {
    void* kargs[] = {
      (void*)&Z0T, (void*)&whh0B, (void*)&b_hh0,
      (void*)&wih1B, (void*)&whh1B, (void*)&b_ih1, (void*)&b_hh1,
      (void*)&HP, (void*)&H1B, (void*)&ZPc, (void*)&KSUM,
      (void*)&flag0, (void*)&flag1
    };
    hipLaunchCooperativeKernel((const void*)lstm_persistent,
                               dim3(128), dim3(512), kargs, 0, stream);
  }
  // Phase D: kbank / vbank
  cvt_bf16<<<dim3(262144/4/256), blk, 0, stream>>>(KSUM, KSB, 262144);
  gemm_bf16<0,0><<<dim3(1024/128, 256/128), blk, 0, stream>>>(
      KSB, wkB, nullptr, KBf, nullptr, 256, 1024, 1024, 1.f/16.f, 1024, nullptr, nullptr);
  vgather<<<256, blk, 0, stream>>>(H1B, VINB);
  gemm_bf16<0,0><<<dim3(1024/128, 256/128), blk, 0, stream>>>(
      VINB, wvB, nullptr, VBf, nullptr, 256, 1024, 1024, 1.f, 1024, nullptr, nullptr);
  // Phase E: retrieval + gate + output
  gemm_bf16<0,0><<<dim3(1024/128, 4096/128), blk, 0, stream>>>(
      H1B, wqB, nullptr, Qf, nullptr, 4096, 1024, 1024, 1.f, 1024, nullptr, nullptr);
  attn_kernel<<<4096, blk, 0, stream>>>(Qf, KBf, VBf, R);
  build_gi_cat<<<4096, blk, 0, stream>>>(H1B, R, GIB, CATB);
  gemm_bf16<1,0><<<dim3(1024/128, 4096/128), blk, 0, stream>>>(
      GIB, wg1B, bg1, nullptr, G1B, 4096, 1024, 3072, 1.f, 1024, nullptr, nullptr);
  // Wg2 GEMM with fused sigmoid+mix epilogue -> MIXB (bf16)
  gemm_bf16<3,0><<<dim3(1024/128, 4096/128), blk, 0, stream>>>(
      G1B, wg2B, bg2, nullptr, MIXB, 4096, 1024, 1024, 1.f, 1024, H1B, R);
  // Wo GEMM with fused masked-cast epilogue -> CATB second half (ldc=2048)
  gemm_bf16<4,0><<<dim3(1024/128, 4096/128), blk, 0, stream>>>(
      MIXB, woB, bo, nullptr, CATB + 1024, 4096, 1024, 1024, 1.f, 2048, nullptr, nullptr);
  gemm_bf16<0,0><<<dim3(1024/128, 4096/128), blk, 0, stream>>>(
      CATB, wfB, bff, FB, nullptr, 4096, 1024, 2048, 1.f, 1024, nullptr, nullptr);
  ln_relu_final<<<4096, blk, 0, stream>>>(FB, g_f, be_f, out);
}

// Round 12
// 1377.669 us; speedup vs baseline: 1.7705x; 1.0258x over previous
//
#include <hip/hip_runtime.h>
#include <hip/hip_bf16.h>
#include <math.h>

#define B_ 16
#define T_ 256
#define D_ 1024
#define H_ 1024
#define S_ 16
#define SCALE_ (1.0f/32.0f)   // 1/sqrt(1024)

typedef __attribute__((ext_vector_type(8))) short short8v;
typedef __attribute__((ext_vector_type(4))) float f32x4;

__device__ __forceinline__ float sigm(float x) { return 1.f / (1.f + expf(-x)); }

__device__ __forceinline__ ushort f2b(float v) {
  __hip_bfloat16 h = __float2bfloat16(v);
  return *reinterpret_cast<ushort*>(&h);
}
__device__ __forceinline__ float b2f(ushort u) {
  union { unsigned u32; float f; } x; x.u32 = ((unsigned)u) << 16; return x.f;
}

__device__ __forceinline__ void glds16(const void* g, void* l) {
  __builtin_amdgcn_global_load_lds((const __attribute__((address_space(1))) void*)g,
                                   (__attribute__((address_space(3))) void*)l, 16, 0, 0);
}

// Poll 64 per-producer flag words with RELAXED agent loads (LLC reads, no
// cache maintenance). h slots are published via LLC-homed atomic exchanges
// and only ever read first-touch after their flag is set.
__device__ __forceinline__ void waitflags64(const int* f, int lane) {
  for (;;) {
    int v = __hip_atomic_load(f + lane, __ATOMIC_RELAXED, __HIP_MEMORY_SCOPE_AGENT);
    if (__all(v != 0)) return;
    __builtin_amdgcn_s_sleep(1);
  }
}

// publish one bf16 pair (even lanes) to a dword slot at the LLC. RMW atomics
// execute at the agent coherence point -- vmcnt ack == LLC arrival, so a
// subsequent flag store (after syncthreads' vmcnt drain) cannot overtake data.
__device__ __forceinline__ void publish_pair(ushort* base, int tid, ushort hb) {
  unsigned hi = (unsigned)__shfl_down((int)hb, 1);
  if (!(tid & 1)) {
    unsigned word = (unsigned)hb | (hi << 16);
    __hip_atomic_exchange((unsigned*)base, word,
                          __ATOMIC_RELAXED, __HIP_MEMORY_SCOPE_AGENT);
  }
}

__device__ __forceinline__ float block_sum256(float v) {
  __shared__ float lds[4];
  #pragma unroll
  for (int off = 32; off; off >>= 1) v += __shfl_down(v, off);
  int w = threadIdx.x >> 6;
  if ((threadIdx.x & 63) == 0) lds[w] = v;
  __syncthreads();
  float r = lds[0] + lds[1] + lds[2] + lds[3];
  __syncthreads();
  return r;
}

// ---------------- fused fp32 -> bf16 convert (all tensors, one launch) ----
#define NJOBS 14
struct CvtJobs {
  const float* src[NJOBS];
  ushort* dst[NJOBS];
  int cum[NJOBS + 1];   // prefix sums in float4 units
};

__global__ __launch_bounds__(256)
void cvt_all(CvtJobs J)
{
  int i = blockIdx.x * 256 + threadIdx.x;
  if (i >= J.cum[NJOBS]) return;
  int j = 0;
  #pragma unroll
  for (int k = 1; k < NJOBS; ++k) j += (i >= J.cum[k]) ? 1 : 0;
  int idx = i - J.cum[j];
  float4 v = ((const float4*)J.src[j])[idx];
  ushort4 o; o.x = f2b(v.x); o.y = f2b(v.y); o.z = f2b(v.z); o.w = f2b(v.w);
  ((ushort4*)J.dst[j])[idx] = o;
}

// ---------------- MFMA bf16 GEMM: C = act(asc * A@Wsel^T + bias) ----------------
// ACT: 0 none, 1 relu, 2 sigmoid,
//      3 mix   (gate=sigm(v); out = gate*h1 + (1-gate)*R, bf16; Hx/Rx row = m)
//      4 masked (out = m>=256 ? v : 0; for the CAT second half)
// W-select: rows m0 < msplit use (W, ascale); else (W2, ascale2).
template<int ACT, int REMAP>
__global__ __launch_bounds__(256)
void gemm_bf16(const ushort* __restrict__ A, const ushort* __restrict__ W,
               const float* __restrict__ bias,
               float* __restrict__ Cf, ushort* __restrict__ Cb,
               int M, int N, int K, float ascale, int ldc,
               const ushort* __restrict__ Hx, const float* __restrict__ Rx,
               const ushort* __restrict__ W2, float ascale2, int msplit)
{
  __shared__ char As[16384];
  __shared__ char Bs[16384];
  const int tid = threadIdx.x;
  const int w = tid >> 6, l = tid & 63;
  const int m0 = blockIdx.y * 128, n0 = blockIdx.x * 128;
  const ushort* __restrict__ Wp = (m0 < msplit) ? W : W2;
  const float asc = (m0 < msplit) ? ascale : ascale2;
  const int wm = w >> 1, wn = w & 1;
  const int srow = l >> 3;
  const int sbyte = ((l & 7) * 16) ^ (srow << 4);
  f32x4 acc[4][4];
  #pragma unroll
  for (int i = 0; i < 4; ++i)
    #pragma unroll
    for (int j = 0; j < 4; ++j) acc[i][j] = (f32x4){0.f, 0.f, 0.f, 0.f};

  for (int k0 = 0; k0 < K; k0 += 64) {
    __syncthreads();
    #pragma unroll
    for (int c = 0; c < 4; ++c) {
      int ca = w * 4 + c;
      int r = ca * 8 + srow;
      glds16((const char*)A + (((size_t)(m0 + r) * K + k0) << 1) + sbyte, As + ca * 1024);
      glds16((const char*)Wp + (((size_t)(n0 + r) * K + k0) << 1) + sbyte, Bs + ca * 1024);
    }
    __syncthreads();
    #pragma unroll
    for (int ks = 0; ks < 2; ++ks) {
      short8v a[4], b[4];
      int qb = ks * 64 + (l >> 4) * 16;
      #pragma unroll
      for (int i = 0; i < 4; ++i) {
        int ra = wm * 64 + i * 16 + (l & 15);
        a[i] = *(const short8v*)(As + ra * 128 + (qb ^ ((ra & 7) << 4)));
        int rb = wn * 64 + i * 16 + (l & 15);
        b[i] = *(const short8v*)(Bs + rb * 128 + (qb ^ ((rb & 7) << 4)));
      }
      #pragma unroll
      for (int i = 0; i < 4; ++i)
        #pragma unroll
        for (int j = 0; j < 4; ++j)
          acc[i][j] = __builtin_amdgcn_mfma_f32_16x16x32_bf16(a[i], b[j], acc[i][j], 0, 0, 0);
    }
  }
  #pragma unroll
  for (int i = 0; i < 4; ++i) {
    #pragma unroll
    for (int j = 0; j < 4; ++j) {
      int n = n0 + wn * 64 + j * 16 + (l & 15);
      float bv = bias ? bias[n] : 0.f;
      #pragma unroll
      for (int q = 0; q < 4; ++q) {
        int m = m0 + wm * 64 + i * 16 + (l >> 4) * 4 + q;
        float v = acc[i][j][q] * asc + bv;
        if (ACT == 1) v = fmaxf(v, 0.f);
        if (ACT == 2) v = sigm(v);
        if (ACT == 3) {
          float gte = sigm(v);
          float h = b2f(Hx[(size_t)m * 1024 + n]);
          float r = Rx[(size_t)m * 1024 + n];
          v = gte * h + (1.f - gte) * r;
        }
        if (ACT == 4) v = (m >= 256) ? v : 0.f;
        size_t off = REMAP ? ((size_t)((m & 255) * 16 + (m >> 8)) * ldc + n)
                           : ((size_t)m * ldc + n);
        if (Cf) Cf[off] = v;
        if (Cb) Cb[off] = f2b(v);
      }
    }
  }
}

// ---------------- LayerNorm+relu: f32 in -> bf16 out ----------------
__global__ __launch_bounds__(256)
void ln_relu_bf16(const float* __restrict__ X, const float* __restrict__ g,
                  const float* __restrict__ be, ushort* __restrict__ out)
{
  size_t row = blockIdx.x;
  const float4* p = (const float4*)(X + row * 1024);
  int tid = threadIdx.x;
  float4 v = p[tid];
  float s = block_sum256(v.x + v.y + v.z + v.w);
  float mean = s * (1.f / 1024.f);
  float dx = v.x - mean, dy = v.y - mean, dz = v.z - mean, dw = v.w - mean;
  float ss = block_sum256(dx*dx + dy*dy + dz*dz + dw*dw);
  float r = rsqrtf(ss * (1.f / 1024.f) + 1e-5f);
  int c4 = tid * 4;
  ushort4 o;
  o.x = f2b(fmaxf(dx * r * g[c4+0] + be[c4+0], 0.f));
  o.y = f2b(fmaxf(dy * r * g[c4+1] + be[c4+1], 0.f));
  o.z = f2b(fmaxf(dz * r * g[c4+2] + be[c4+2], 0.f));
  o.w = f2b(fmaxf(dw * r * g[c4+3] + be[c4+3], 0.f));
  *(ushort4*)(out + row * 1024 + c4) = o;
}

// final LN+relu: rows (t*B+b) f32 -> out [b][t][h] f32
__global__ __launch_bounds__(256)
void ln_relu_final(const float* __restrict__ F, const float* __restrict__ g,
                   const float* __restrict__ be, float* __restrict__ out)
{
  int row = blockIdx.x;           // t*16 + b
  int t = row >> 4, b = row & 15;
  const float4* p = (const float4*)(F + (size_t)row * 1024);
  int tid = threadIdx.x;
  float4 v = p[tid];
  float s = block_sum256(v.x + v.y + v.z + v.w);
  float mean = s * (1.f / 1024.f);
  float dx = v.x - mean, dy = v.y - mean, dz = v.z - mean, dw = v.w - mean;
  float ss = block_sum256(dx*dx + dy*dy + dz*dz + dw*dw);
  float r = rsqrtf(ss * (1.f / 1024.f) + 1e-5f);
  int c4 = tid * 4;
  float4 o;
  o.x = fmaxf(dx * r * g[c4+0] + be[c4+0], 0.f);
  o.y = fmaxf(dy * r * g[c4+1] + be[c4+1], 0.f);
  o.z = fmaxf(dz * r * g[c4+2] + be[c4+2], 0.f);
  o.w = fmaxf(dw * r * g[c4+3] + be[c4+3], 0.f);
  ((float4*)(out + ((size_t)b * T_ + t) * 1024))[tid] = o;
}

// ---------------- persistent cooperative LSTM (all 256 steps) ----------------
// VERBATIM the round-8/round-10 version (passed determinism re-validation):
// blocks 0..63 layer 0, 64..127 layer 1; weights in VGPRs, c in registers.
// h published via LLC-homed atomic exchanges -> syncthreads (vmcnt drain ==
// LLC completion) -> relaxed flag store. Consumers: designated-wave relaxed
// polls + plain first-touch reads. DO NOT add tighter consumers or reorder
// polls/staging: r7/r9/r11 all failed bit-determinism from sub-us-window
// stale reads. This structure is frozen.
__global__ __launch_bounds__(512)
void lstm_persistent(const ushort* __restrict__ Z0T,   // [T*B,4096] bf16
                     const ushort* __restrict__ whh0,  // [4096,1024]
                     const float* __restrict__ bhh0,
                     const ushort* __restrict__ wih1,  // [4096,1024]
                     const ushort* __restrict__ whh1,  // [4096,1024]
                     const float* __restrict__ bih1,
                     const float* __restrict__ bhh1,
                     ushort* __restrict__ HP,          // [257][16][1024], slot0 zeroed
                     ushort* __restrict__ H1B,         // [256][16][1024]
                     const ushort* __restrict__ ZP,    // 32KB zeros (h1 at t=-1)
                     float* __restrict__ KSUM,         // [S*B,1024] f32
                     int* flag0,                       // [257][64]
                     int* flag1)                       // [256][64]
{
  __shared__ char Ah[65536];
  __shared__ float zs[8][16][16];
  __builtin_amdgcn_fence(__ATOMIC_ACQUIRE, "agent");   // once: clear stale lines
  const int tid = threadIdx.x, w = tid >> 6, l = tid & 63;
  const int lm = l & 15, lq = l >> 4;
  const int g = w & 3, kh = w >> 2;
  const int jb = blockIdx.x & 63;
  const int j0 = jb * 16;
  const int eb = tid >> 4, ej = tid & 15, jf = j0 + ej;   // tid<256 only
  float creg = 0.f;
  float br[4];

  if (blockIdx.x < 64) {
    // ================= layer 0 =================
    short8v wreg[16];
    {
      const int n = g * 1024 + j0 + lm;
      const ushort* wb = whh0 + (size_t)n * 1024 + kh * 512 + lq * 8;
      #pragma unroll
      for (int ks = 0; ks < 16; ++ks) wreg[ks] = *(const short8v*)(wb + ks * 32);
    }
    if (tid < 256) {
      #pragma unroll
      for (int gg = 0; gg < 4; ++gg) br[gg] = bhh0[gg * 1024 + jf];
    }
    for (int t = 0; t < T_; ++t) {
      // prefetch Z0 gate pre-activations (static data) before the spin
      float z0v[4];
      if (tid < 256) {
        const ushort* zp = Z0T + ((size_t)t * 16 + eb) * 4096 + jf;
        #pragma unroll
        for (int gg = 0; gg < 4; ++gg) z0v[gg] = b2f(zp[gg * 1024]);
      }
      if (t > 0) {
        if (w == 0) waitflags64(flag0 + (size_t)t * 64, l);
        __syncthreads();
      }
      const ushort* hin = HP + (size_t)t * 16384;
      #pragma unroll
      for (int it = 0; it < 4; ++it) {
        int g1k = w * 4 + it;             // 0..31 (1KB chunks)
        int kc = g1k * 4 + lq;            // 0..127
        int m = lm ^ (kc & 15);
        glds16(hin + (size_t)m * 1024 + kc * 8, Ah + g1k * 1024);
      }
      __syncthreads();
      {
        f32x4 a0 = {0.f,0.f,0.f,0.f}, a1 = {0.f,0.f,0.f,0.f};
        #pragma unroll
        for (int ks = 0; ks < 16; ks += 2) {
          int kc0 = kh * 64 + ks * 4 + lq;
          int kc1 = kc0 + 4;
          short8v f0 = *(const short8v*)(Ah + kc0 * 256 + ((lm ^ (kc0 & 15)) << 4));
          short8v f1 = *(const short8v*)(Ah + kc1 * 256 + ((lm ^ (kc1 & 15)) << 4));
          a0 = __builtin_amdgcn_mfma_f32_16x16x32_bf16(f0, wreg[ks],     a0, 0, 0, 0);
          a1 = __builtin_amdgcn_mfma_f32_16x16x32_bf16(f1, wreg[ks + 1], a1, 0, 0, 0);
        }
        #pragma unroll
        for (int q = 0; q < 4; ++q) zs[w][lq * 4 + q][lm] = a0[q] + a1[q];
      }
      __syncthreads();
      if (tid < 256) {
        float zi = zs[0][eb][ej] + zs[4][eb][ej] + z0v[0] + br[0];
        float zf = zs[1][eb][ej] + zs[5][eb][ej] + z0v[1] + br[1];
        float zg = zs[2][eb][ej] + zs[6][eb][ej] + z0v[2] + br[2];
        float zo = zs[3][eb][ej] + zs[7][eb][ej] + z0v[3] + br[3];
        float cp = sigm(zf) * creg + sigm(zi) * tanhf(zg);
        creg = cp;
        ushort hb = f2b(sigm(zo) * tanhf(cp));
        publish_pair(HP + (size_t)(t + 1) * 16384 + eb * 1024 + jf, tid, hb);
      }
      __syncthreads();   // vmcnt drain: atomic swaps completed AT THE LLC
      if (tid == 0)
        __hip_atomic_store(flag0 + (size_t)(t + 1) * 64 + jb, 1,
                           __ATOMIC_RELAXED, __HIP_MEMORY_SCOPE_AGENT);
    }
  } else {
    // ================= layer 1 =================
    short8v wreg[32];
    {
      const int n = g * 1024 + j0 + lm;
      const ushort* wb = (kh ? whh1 : wih1) + (size_t)n * 1024 + lq * 8;
      #pragma unroll
      for (int ks = 0; ks < 32; ++ks) wreg[ks] = *(const short8v*)(wb + ks * 32);
    }
    if (tid < 256) {
      #pragma unroll
      for (int gg = 0; gg < 4; ++gg)
        br[gg] = bih1[gg * 1024 + jf] + bhh1[gg * 1024 + jf];
    }
    float ksr = 0.f;
    for (int t = 0; t < T_; ++t) {
      // h0(t) is produced by the (lighter, ahead-running) L0 chain -- usually
      // already flagged. Stage it FIRST, then overlap its read latency with
      // the own-chain flag1 wait (the critical edge).
      if (w == 0) waitflags64(flag0 + (size_t)(t + 1) * 64, l);
      __syncthreads();
      const ushort* h0n = HP + (size_t)(t + 1) * 16384;
      #pragma unroll
      for (int it = 0; it < 4; ++it) {
        int g1k = w * 4 + it;             // chunks 0..31 -> kc 0..127 (h0)
        int kc = g1k * 4 + lq;
        int m = lm ^ (kc & 15);
        glds16(h0n + (size_t)m * 1024 + kc * 8, Ah + g1k * 1024);
      }
      if (w == 1 && t > 0) waitflags64(flag1 + (size_t)(t - 1) * 64, l);
      __syncthreads();   // flag1 confirmed; h0 loads drained per-wave here
      const ushort* h1p = (t > 0) ? (H1B + (size_t)(t - 1) * 16384) : ZP;
      #pragma unroll
      for (int it = 0; it < 4; ++it) {
        int g1k = 32 + w * 4 + it;        // chunks 32..63 -> kc 128..255 (h1)
        int kc = g1k * 4 + lq;
        int m = lm ^ (kc & 15);
        glds16(h1p + (size_t)m * 1024 + (kc - 128) * 8, Ah + g1k * 1024);
      }
      __syncthreads();
      {
        f32x4 a0 = {0.f,0.f,0.f,0.f}, a1 = {0.f,0.f,0.f,0.f};
        #pragma unroll
        for (int ks = 0; ks < 32; ks += 2) {
          int kc0 = kh * 128 + ks * 4 + lq;
          int kc1 = kc0 + 4;
          short8v f0 = *(const short8v*)(Ah + kc0 * 256 + ((lm ^ (kc0 & 15)) << 4));
          short8v f1 = *(const short8v*)(Ah + kc1 * 256 + ((lm ^ (kc1 & 15)) << 4));
          a0 = __builtin_amdgcn_mfma_f32_16x16x32_bf16(f0, wreg[ks],     a0, 0, 0, 0);
          a1 = __builtin_amdgcn_mfma_f32_16x16x32_bf16(f1, wreg[ks + 1], a1, 0, 0, 0);
        }
        #pragma unroll
        for (int q = 0; q < 4; ++q) zs[w][lq * 4 + q][lm] = a0[q] + a1[q];
      }
      __syncthreads();
      if (tid < 256) {
        float zi = zs[0][eb][ej] + zs[4][eb][ej] + br[0];
        float zf = zs[1][eb][ej] + zs[5][eb][ej] + br[1];
        float zg = zs[2][eb][ej] + zs[6][eb][ej] + br[2];
        float zo = zs[3][eb][ej] + zs[7][eb][ej] + br[3];
        float cp = sigm(zf) * creg + sigm(zi) * tanhf(zg);
        creg = cp;
        float hv = sigm(zo) * tanhf(cp);
        ksr += hv;
        publish_pair(H1B + (size_t)t * 16384 + eb * 1024 + jf, tid, f2b(hv));
        if ((t & 15) == 15) {
          KSUM[((size_t)(t >> 4) * 16 + eb) * 1024 + jf] = ksr;   // post-kernel consumer
          ksr = 0.f;
        }
      }
      __syncthreads();   // vmcnt drain: swaps completed at LLC
      if (tid == 0)
        __hip_atomic_store(flag1 + (size_t)t * 64 + jb, 1,
                           __ATOMIC_RELAXED, __HIP_MEMORY_SCOPE_AGENT);
    }
  }
}

// prep_banks: cvt KSUM->bf16 and gather segment-final h1 rows, one launch.
// KSB and VINB are CONTIGUOUS ([512,1024] total) so one GEMM handles both.
__global__ __launch_bounds__(256)
void prep_banks(const float* __restrict__ KSUM, ushort* __restrict__ KSB,
                const ushort* __restrict__ H1B)
{
  int r = blockIdx.x;             // 0..255 (s*16+b)
  int c4 = threadIdx.x * 4;
  float4 v = *(const float4*)(KSUM + (size_t)r * 1024 + c4);
  ushort4 o; o.x = f2b(v.x); o.y = f2b(v.y); o.z = f2b(v.z); o.w = f2b(v.w);
  *(ushort4*)(KSB + (size_t)r * 1024 + c4) = o;
  int src = (r >> 4) * 256 + 240 + (r & 15);
  *(ushort4*)(KSB + (size_t)(256 + r) * 1024 + c4) =
      *(const ushort4*)(H1B + (size_t)src * 1024 + c4);
}

// fused: per-(b,t) masked softmax attention (bf16 Q/banks) + R write +
// GI = [h1, R, h1-R] + CAT first half (= h1)
__global__ __launch_bounds__(256)
void attn_gi_cat(const ushort* __restrict__ Q, const ushort* __restrict__ kbank,
                 const ushort* __restrict__ vbank, const ushort* __restrict__ H1B,
                 float* __restrict__ R, ushort* __restrict__ GI,
                 ushort* __restrict__ CATB)
{
  int row = blockIdx.x;          // t*16 + b
  int t = row >> 4, b = row & 15;
  int si = t >> 4;
  int tid = threadIdx.x, lane = tid & 63, w = tid >> 6;
  __shared__ float sc[16];
  float4 accv = {0.f, 0.f, 0.f, 0.f};
  if (si > 0) {
    const ushort* q = Q + (size_t)row * 1024;
    for (int s = w; s < si; s += 4) {
      const ushort* kk = kbank + ((size_t)s * 16 + b) * 1024;
      float p = 0.f;
      for (int k = lane; k < 1024; k += 64) p += b2f(q[k]) * b2f(kk[k]);
      #pragma unroll
      for (int off = 32; off; off >>= 1) p += __shfl_down(p, off);
      if (lane == 0) sc[s] = p * SCALE_;
    }
    __syncthreads();
    float mx = -1e30f;
    for (int s = 0; s < si; ++s) mx = fmaxf(mx, sc[s]);
    float den = 0.f;
    for (int s = 0; s < si; ++s) den += expf(sc[s] - mx);
    float inv = 1.f / den;
    for (int s = 0; s < si; ++s) {
      float a = expf(sc[s] - mx) * inv;
      ushort4 vv = *(const ushort4*)(vbank + ((size_t)s * 16 + b) * 1024 + tid * 4);
      accv.x += a * b2f(vv.x); accv.y += a * b2f(vv.y);
      accv.z += a * b2f(vv.z); accv.w += a * b2f(vv.w);
    }
  }
  size_t r = row;
  int c4 = tid * 4;
  ((float4*)(R + r * 1024))[tid] = accv;
  ushort4 h4 = *(const ushort4*)(H1B + r * 1024 + c4);
  *(ushort4*)(GI + r * 3072 + c4) = h4;
  ushort4 rb; rb.x = f2b(accv.x); rb.y = f2b(accv.y);
  rb.z = f2b(accv.z); rb.w = f2b(accv.w);
  *(ushort4*)(GI + r * 3072 + 1024 + c4) = rb;
  ushort4 d;
  d.x = f2b(b2f(h4.x) - accv.x); d.y = f2b(b2f(h4.y) - accv.y);
  d.z = f2b(b2f(h4.z) - accv.z); d.w = f2b(b2f(h4.w) - accv.w);
  *(ushort4*)(GI + r * 3072 + 2048 + c4) = d;
  *(ushort4*)(CATB + r * 2048 + c4) = h4;
}

extern "C" void kernel_launch(void* const* d_in, const int* in_sizes, int n_in,
                              void* d_out, int out_size, void* d_ws, size_t ws_size,
                              hipStream_t stream) {
  const float* x     = (const float*)d_in[0];
  const float* W_ip  = (const float*)d_in[1];
  const float* b_ip  = (const float*)d_in[2];
  const float* g_ip  = (const float*)d_in[3];
  const float* be_ip = (const float*)d_in[4];
  const float* W_ih0 = (const float*)d_in[5];
  const float* W_hh0 = (const float*)d_in[6];
  const float* b_ih0 = (const float*)d_in[7];
  const float* b_hh0 = (const float*)d_in[8];
  const float* W_ih1 = (const float*)d_in[9];
  const float* W_hh1 = (const float*)d_in[10];
  const float* b_ih1 = (const float*)d_in[11];
  const float* b_hh1 = (const float*)d_in[12];
  const float* Wq    = (const float*)d_in[13];
  const float* Wk    = (const float*)d_in[14];
  const float* Wv    = (const float*)d_in[15];
  const float* Wg1   = (const float*)d_in[16];
  const float* bg1   = (const float*)d_in[17];
  const float* Wg2   = (const float*)d_in[18];
  const float* bg2   = (const float*)d_in[19];
  const float* Wo    = (const float*)d_in[20];
  const float* bo    = (const float*)d_in[21];
  const float* Wf    = (const float*)d_in[22];
  const float* bff   = (const float*)d_in[23];
  const float* g_f   = (const float*)d_in[24];
  const float* be_f  = (const float*)d_in[25];
  float* out = (float*)d_out;
  char* ws = (char*)d_ws;
  const size_t MB = (size_t)1 << 20;
  const size_t KB = (size_t)1 << 10;

  // bf16 weight pool (offsets in elements)
  ushort* WB = (ushort*)(ws);
  ushort* wipB  = WB;             // 1M
  ushort* wih0B = WB + 1*1048576; // 4M
  ushort* whh0B = WB + 5*1048576;
  ushort* wih1B = WB + 9*1048576;
  ushort* whh1B = WB + 13*1048576;
  ushort* wqB   = WB + 17*1048576;
  ushort* wkB   = WB + 18*1048576;
  ushort* wvB   = WB + 19*1048576;
  ushort* wg1B  = WB + 20*1048576; // 3M
  ushort* wg2B  = WB + 23*1048576;
  ushort* woB   = WB + 24*1048576;
  ushort* wfB   = WB + 25*1048576; // 2M -> ends 27M elems = 54MB

  ushort* XB   = (ushort*)(ws + 54 * MB);   // 8MB: x bf16, later XPB
  float*  XP   = (float*)(ws + 62 * MB);    // 16MB: input_proj pre-LN
  ushort* QB   = (ushort*)(ws + 62 * MB);   // 8MB bf16 Q (after LN consumed XP)
  char*   SCR  = ws + 78 * MB;              // 48MB scratch region
  ushort* Z0T  = (ushort*)SCR;              // 32MB bf16 [T*B,4096] (phase B/C)
  // post-loop overlays (Z0T dead after phase C):
  ushort* GIB  = (ushort*)SCR;              // 24MB  [4096,3072]
  ushort* CATB = (ushort*)(SCR + 24 * MB);  // 16MB  [4096,2048]
  ushort* G1B  = (ushort*)(SCR + 40 * MB);  // 8MB   [4096,1024]
  ushort* MIXB = (ushort*)SCR;              // 8MB (reuses GIB after Wg1)
  float*  FB   = (float*)SCR;               // 16MB (reuses MIXB after Wo)
  ushort* H1B  = (ushort*)(ws + 126 * MB);  // 8MB
  // HP lives in the R region during phase C (R is written only afterwards)
  ushort* HP   = (ushort*)(ws + 134 * MB);  // 257*32KB = 8.22MB
  float*  R    = (float*)(ws + 134 * MB);   // 16MB (after phase C)
  char*   ST   = ws + 150 * MB;
  int*    flag0 = (int*)(ST);                     // [257][64] = 65.8KB
  int*    flag1 = (int*)(ST + 68 * KB);           // [256][64] = 64KB
  const ushort* ZPc = (const ushort*)(ST + 132 * KB);   // 32KB zeros
  float*  KSUM = (float*)(ST + 192 * KB);         // 1MB
  ushort* KSB  = (ushort*)(ST + 1216 * KB);       // [512,1024] bf16 = 1MB
                                                  //   rows 0-255 K-input,
                                                  //   rows 256-511 V-input
  ushort* KBb  = (ushort*)(ST + 2240 * KB);       // [512,1024] bf16 = 1MB
                                                  //   rows 0-255 kbank,
                                                  //   rows 256-511 vbank
  ushort* VBb  = KBb + 256 * 1024;

  // zero flags + h1(-1) zero-page; HP slot0 zeroed separately
  hipMemsetAsync(ST, 0, 164 * KB, stream);
  hipMemsetAsync(HP, 0, 32 * KB, stream);

  dim3 blk(256);
  // fused weight + input conversion (single launch)
  {
    CvtJobs J;
    const float* srcs[NJOBS] = { x, W_ip, W_ih0, W_hh0, W_ih1, W_hh1,
                                 Wq, Wk, Wv, Wg1, Wg2, Wo, Wf, nullptr };
    ushort* dsts[NJOBS] = { XB, wipB, wih0B, whh0B, wih1B, whh1B,
                            wqB, wkB, wvB, wg1B, wg2B, woB, wfB, nullptr };
    int n4[NJOBS] = { 1048576, 262144, 1048576, 1048576, 1048576, 1048576,
                      262144, 262144, 262144, 786432, 262144, 262144,
                      524288, 0 };
    int c = 0;
    for (int j = 0; j < NJOBS; ++j) {
      J.src[j] = srcs[j] ? srcs[j] : x;
      J.dst[j] = dsts[j] ? dsts[j] : XB;
      J.cum[j] = c;
      c += n4[j];
    }
    J.cum[NJOBS] = c;                    // 8,126,464 float4 items
    cvt_all<<<dim3((c + 255) / 256), blk, 0, stream>>>(J);
  }

  const int BIG = 1 << 30;
  // Phase A: XP = x@W_ip^T + b_ip ; XPB = relu(LN(XP)) (bf16, stored in XB)
  gemm_bf16<0,0><<<dim3(1024/128, 4096/128), blk, 0, stream>>>(
      XB, wipB, b_ip, XP, nullptr, 4096, 1024, 1024, 1.f, 1024,
      nullptr, nullptr, wipB, 1.f, BIG);
  ln_relu_bf16<<<4096, blk, 0, stream>>>(XP, g_ip, be_ip, XB);
  // Phase B: Z0T = XPB@W_ih0^T + b_ih0, rows remapped to t*16+b, bf16
  gemm_bf16<0,1><<<dim3(4096/128, 4096/128), blk, 0, stream>>>(
      XB, wih0B, b_ih0, nullptr, Z0T, 4096, 4096, 1024, 1.f, 4096,
      nullptr, nullptr, wih0B, 1.f, BIG);
  // Phase C: single persistent cooperative kernel, all 256 steps (frozen)
  {
    void* kargs[] = {
      (void*)&Z0T, (void*)&whh0B, (void*)&b_hh0,
      (void*)&wih1B, (void*)&whh1B, (void*)&b_ih1, (void*)&b_hh1,
      (void*)&HP, (void*)&H1B, (void*)&ZPc, (void*)&KSUM,
      (void*)&flag0, (void*)&flag1
    };
    hipLaunchCooperativeKernel((const void*)lstm_persistent,
                               dim3(128), dim3(512), kargs, 0, stream);
  }
  // Phase D: prep inputs, then ONE merged GEMM: rows<256 -> kbank (Wk, /16),
  // rows>=256 -> vbank (Wv, x1); outputs contiguous KBb/VBb.
  prep_banks<<<256, blk, 0, stream>>>(KSUM, KSB, H1B);
  gemm_bf16<0,0><<<dim3(1024/128, 512/128), blk, 0, stream>>>(
      KSB, wkB, nullptr, nullptr, KBb, 512, 1024, 1024, 1.f/16.f, 1024,
      nullptr, nullptr, wvB, 1.f, 256);
  // Phase E: Q (bf16 out) -> fused attention+GI+CAT -> gate MLP -> output
  gemm_bf16<0,0><<<dim3(1024/128, 4096/128), blk, 0, stream>>>(
      H1B, wqB, nullptr, nullptr, QB, 4096, 1024, 1024, 1.f, 1024,
      nullptr, nullptr, wqB, 1.f, BIG);
  attn_gi_cat<<<4096, blk, 0, stream>>>(QB, KBb, VBb, H1B, R, GIB, CATB);
  gemm_bf16<1,0><<<dim3(1024/128, 4096/128), blk, 0, stream>>>(
      GIB, wg1B, bg1, nullptr, G1B, 4096, 1024, 3072, 1.f, 1024,
      nullptr, nullptr, wg1B, 1.f, BIG);
  // Wg2 GEMM with fused sigmoid+mix epilogue -> MIXB (bf16)
  gemm_bf16<3,0><<<dim3(1024/128, 4096/128), blk, 0, stream>>>(
      G1B, wg2B, bg2, nullptr, MIXB, 4096, 1024, 1024, 1.f, 1024,
      H1B, R, wg2B, 1.f, BIG);
  // Wo GEMM with fused masked-cast epilogue -> CATB second half (ldc=2048)
  gemm_bf16<4,0><<<dim3(1024/128, 4096/128), blk, 0, stream>>>(
      MIXB, woB, bo, nullptr, CATB + 1024, 4096, 1024, 1024, 1.f, 2048,
      nullptr, nullptr, woB, 1.f, BIG);
  gemm_bf16<0,0><<<dim3(1024/128, 4096/128), blk, 0, stream>>>(
      CATB, wfB, bff, FB, nullptr, 4096, 1024, 2048, 1.f, 1024,
      nullptr, nullptr, wfB, 1.f, BIG);
  ln_relu_final<<<4096, blk, 0, stream>>>(FB, g_f, be_f, out);
}

// Round 13
// 1355.403 us; speedup vs baseline: 1.7996x; 1.0164x over previous
//
#include <hip/hip_runtime.h>
#include <hip/hip_bf16.h>
#include <math.h>

#define B_ 16
#define T_ 256
#define D_ 1024
#define H_ 1024
#define S_ 16
#define SCALE_ (1.0f/32.0f)   // 1/sqrt(1024)

typedef __attribute__((ext_vector_type(8))) short short8v;
typedef __attribute__((ext_vector_type(4))) float f32x4;

__device__ __forceinline__ float sigm(float x) { return 1.f / (1.f + expf(-x)); }

__device__ __forceinline__ ushort f2b(float v) {
  __hip_bfloat16 h = __float2bfloat16(v);
  return *reinterpret_cast<ushort*>(&h);
}
__device__ __forceinline__ float b2f(ushort u) {
  union { unsigned u32; float f; } x; x.u32 = ((unsigned)u) << 16; return x.f;
}

__device__ __forceinline__ void glds16(const void* g, void* l) {
  __builtin_amdgcn_global_load_lds((const __attribute__((address_space(1))) void*)g,
                                   (__attribute__((address_space(3))) void*)l, 16, 0, 0);
}

// Poll 64 per-producer flag words with RELAXED agent loads (LLC reads, no
// cache maintenance). h slots are published via LLC-homed atomic exchanges
// and only ever read first-touch after their flag is set.
__device__ __forceinline__ void waitflags64(const int* f, int lane) {
  for (;;) {
    int v = __hip_atomic_load(f + lane, __ATOMIC_RELAXED, __HIP_MEMORY_SCOPE_AGENT);
    if (__all(v != 0)) return;
    __builtin_amdgcn_s_sleep(1);
  }
}

// publish one bf16 pair (even lanes) to a dword slot at the LLC. RMW atomics
// execute at the agent coherence point -- vmcnt ack == LLC arrival, so a
// subsequent flag store (after syncthreads' vmcnt drain) cannot overtake data.
__device__ __forceinline__ void publish_pair(ushort* base, int tid, ushort hb) {
  unsigned hi = (unsigned)__shfl_down((int)hb, 1);
  if (!(tid & 1)) {
    unsigned word = (unsigned)hb | (hi << 16);
    __hip_atomic_exchange((unsigned*)base, word,
                          __ATOMIC_RELAXED, __HIP_MEMORY_SCOPE_AGENT);
  }
}

__device__ __forceinline__ float block_sum256(float v) {
  __shared__ float lds[4];
  #pragma unroll
  for (int off = 32; off; off >>= 1) v += __shfl_down(v, off);
  int w = threadIdx.x >> 6;
  if ((threadIdx.x & 63) == 0) lds[w] = v;
  __syncthreads();
  float r = lds[0] + lds[1] + lds[2] + lds[3];
  __syncthreads();
  return r;
}

// ---------------- fused fp32 -> bf16 convert (bulk tensors, one launch) ----
#define NJOBS 12
struct CvtJobs {
  const float* src[NJOBS];
  ushort* dst[NJOBS];
  int cum[NJOBS + 1];   // prefix sums in float4 units
};

__global__ __launch_bounds__(256)
void cvt_all(CvtJobs J)
{
  int i = blockIdx.x * 256 + threadIdx.x;
  if (i >= J.cum[NJOBS]) return;
  int j = 0;
  #pragma unroll
  for (int k = 1; k < NJOBS; ++k) j += (i >= J.cum[k]) ? 1 : 0;
  int idx = i - J.cum[j];
  float4 v = ((const float4*)J.src[j])[idx];
  ushort4 o; o.x = f2b(v.x); o.y = f2b(v.y); o.z = f2b(v.z); o.w = f2b(v.w);
  ((ushort4*)J.dst[j])[idx] = o;
}

// transpose + cvt: dst[i,j] = bf16(src[j,i]) for 1024x1024
__global__ __launch_bounds__(256)
void tr_cvt(const float* __restrict__ src, ushort* __restrict__ dst)
{
  __shared__ float tile[64][65];
  const int bx = blockIdx.x, by = blockIdx.y;
  const int tx = threadIdx.x & 15, ty = threadIdx.x >> 4;
  #pragma unroll
  for (int p = 0; p < 4; ++p) {
    int r = p * 16 + ty;
    float4 v = *(const float4*)(src + (size_t)(by * 64 + r) * 1024 + bx * 64 + tx * 4);
    tile[r][tx*4+0] = v.x; tile[r][tx*4+1] = v.y;
    tile[r][tx*4+2] = v.z; tile[r][tx*4+3] = v.w;
  }
  __syncthreads();
  #pragma unroll
  for (int p = 0; p < 4; ++p) {
    int c = p * 16 + ty;
    ushort4 o;
    o.x = f2b(tile[tx*4+0][c]); o.y = f2b(tile[tx*4+1][c]);
    o.z = f2b(tile[tx*4+2][c]); o.w = f2b(tile[tx*4+3][c]);
    *(ushort4*)(dst + (size_t)(bx * 64 + c) * 1024 + by * 64 + tx * 4) = o;
  }
}

// fold Wg1 [1024,3072] -> [Wh|Wr] [1024,2048] bf16:
//   Wh = Wa + Wc, Wr = Wb - Wc  (gi=[h1,R,h1-R] => h1@Wh^T + R@Wr^T)
__global__ __launch_bounds__(256)
void wg1_fold(const float* __restrict__ Wg1, ushort* __restrict__ dst)
{
  int n = blockIdx.x;
  int c4 = threadIdx.x * 4;
  const float* row = Wg1 + (size_t)n * 3072;
  float4 a = *(const float4*)(row + c4);
  float4 b = *(const float4*)(row + 1024 + c4);
  float4 c = *(const float4*)(row + 2048 + c4);
  ushort4 h, r;
  h.x = f2b(a.x + c.x); h.y = f2b(a.y + c.y);
  h.z = f2b(a.z + c.z); h.w = f2b(a.w + c.w);
  r.x = f2b(b.x - c.x); r.y = f2b(b.y - c.y);
  r.z = f2b(b.z - c.z); r.w = f2b(b.w - c.w);
  *(ushort4*)(dst + (size_t)n * 2048 + c4) = h;
  *(ushort4*)(dst + (size_t)n * 2048 + 1024 + c4) = r;
}

// ---------------- MFMA bf16 GEMM: C = act(asc * A@Wsel^T + bias) ----------------
// ACT: 0 none, 1 relu,
//      3 mix   (gate=sigm(v); out = gate*h1 + (1-gate)*R; Hx stride 1024,
//               Rxb bf16 stride 2048)
//      4 masked (out = m>=256 ? v : 0)
// W-select: rows m0 < msplit use (W, ascale); else (W2, ascale2).
template<int ACT, int REMAP>
__global__ __launch_bounds__(256)
void gemm_bf16(const ushort* __restrict__ A, const ushort* __restrict__ W,
               const float* __restrict__ bias,
               float* __restrict__ Cf, ushort* __restrict__ Cb,
               int M, int N, int K, float ascale, int ldc,
               const ushort* __restrict__ Hx, const ushort* __restrict__ Rxb,
               const ushort* __restrict__ W2, float ascale2, int msplit)
{
  __shared__ char As[16384];
  __shared__ char Bs[16384];
  const int tid = threadIdx.x;
  const int w = tid >> 6, l = tid & 63;
  const int m0 = blockIdx.y * 128, n0 = blockIdx.x * 128;
  const ushort* __restrict__ Wp = (m0 < msplit) ? W : W2;
  const float asc = (m0 < msplit) ? ascale : ascale2;
  const int wm = w >> 1, wn = w & 1;
  const int srow = l >> 3;
  const int sbyte = ((l & 7) * 16) ^ (srow << 4);
  f32x4 acc[4][4];
  #pragma unroll
  for (int i = 0; i < 4; ++i)
    #pragma unroll
    for (int j = 0; j < 4; ++j) acc[i][j] = (f32x4){0.f, 0.f, 0.f, 0.f};

  for (int k0 = 0; k0 < K; k0 += 64) {
    __syncthreads();
    #pragma unroll
    for (int c = 0; c < 4; ++c) {
      int ca = w * 4 + c;
      int r = ca * 8 + srow;
      glds16((const char*)A + (((size_t)(m0 + r) * K + k0) << 1) + sbyte, As + ca * 1024);
      glds16((const char*)Wp + (((size_t)(n0 + r) * K + k0) << 1) + sbyte, Bs + ca * 1024);
    }
    __syncthreads();
    #pragma unroll
    for (int ks = 0; ks < 2; ++ks) {
      short8v a[4], b[4];
      int qb = ks * 64 + (l >> 4) * 16;
      #pragma unroll
      for (int i = 0; i < 4; ++i) {
        int ra = wm * 64 + i * 16 + (l & 15);
        a[i] = *(const short8v*)(As + ra * 128 + (qb ^ ((ra & 7) << 4)));
        int rb = wn * 64 + i * 16 + (l & 15);
        b[i] = *(const short8v*)(Bs + rb * 128 + (qb ^ ((rb & 7) << 4)));
      }
      #pragma unroll
      for (int i = 0; i < 4; ++i)
        #pragma unroll
        for (int j = 0; j < 4; ++j)
          acc[i][j] = __builtin_amdgcn_mfma_f32_16x16x32_bf16(a[i], b[j], acc[i][j], 0, 0, 0);
    }
  }
  #pragma unroll
  for (int i = 0; i < 4; ++i) {
    #pragma unroll
    for (int j = 0; j < 4; ++j) {
      int n = n0 + wn * 64 + j * 16 + (l & 15);
      float bv = bias ? bias[n] : 0.f;
      #pragma unroll
      for (int q = 0; q < 4; ++q) {
        int m = m0 + wm * 64 + i * 16 + (l >> 4) * 4 + q;
        float v = acc[i][j][q] * asc + bv;
        if (ACT == 1) v = fmaxf(v, 0.f);
        if (ACT == 3) {
          float gte = sigm(v);
          float h = b2f(Hx[(size_t)m * 1024 + n]);
          float r = b2f(Rxb[(size_t)m * 2048 + n]);
          v = gte * h + (1.f - gte) * r;
        }
        if (ACT == 4) v = (m >= 256) ? v : 0.f;
        size_t off = REMAP ? ((size_t)((m & 255) * 16 + (m >> 8)) * ldc + n)
                           : ((size_t)m * ldc + n);
        if (Cf) Cf[off] = v;
        if (Cb) Cb[off] = f2b(v);
      }
    }
  }
}

// ---------------- LayerNorm+relu: bf16 in -> bf16 out ----------------
__global__ __launch_bounds__(256)
void ln_relu_bf16(const ushort* __restrict__ X, const float* __restrict__ g,
                  const float* __restrict__ be, ushort* __restrict__ out)
{
  size_t row = blockIdx.x;
  int tid = threadIdx.x;
  ushort4 u = *(const ushort4*)(X + row * 1024 + tid * 4);
  float vx = b2f(u.x), vy = b2f(u.y), vz = b2f(u.z), vw = b2f(u.w);
  float s = block_sum256(vx + vy + vz + vw);
  float mean = s * (1.f / 1024.f);
  float dx = vx - mean, dy = vy - mean, dz = vz - mean, dw = vw - mean;
  float ss = block_sum256(dx*dx + dy*dy + dz*dz + dw*dw);
  float r = rsqrtf(ss * (1.f / 1024.f) + 1e-5f);
  int c4 = tid * 4;
  ushort4 o;
  o.x = f2b(fmaxf(dx * r * g[c4+0] + be[c4+0], 0.f));
  o.y = f2b(fmaxf(dy * r * g[c4+1] + be[c4+1], 0.f));
  o.z = f2b(fmaxf(dz * r * g[c4+2] + be[c4+2], 0.f));
  o.w = f2b(fmaxf(dw * r * g[c4+3] + be[c4+3], 0.f));
  *(ushort4*)(out + row * 1024 + c4) = o;
}

// final LN+relu: rows (t*B+b) f32 -> out [b][t][h] f32
__global__ __launch_bounds__(256)
void ln_relu_final(const float* __restrict__ F, const float* __restrict__ g,
                   const float* __restrict__ be, float* __restrict__ out)
{
  int row = blockIdx.x;           // t*16 + b
  int t = row >> 4, b = row & 15;
  const float4* p = (const float4*)(F + (size_t)row * 1024);
  int tid = threadIdx.x;
  float4 v = p[tid];
  float s = block_sum256(v.x + v.y + v.z + v.w);
  float mean = s * (1.f / 1024.f);
  float dx = v.x - mean, dy = v.y - mean, dz = v.z - mean, dw = v.w - mean;
  float ss = block_sum256(dx*dx + dy*dy + dz*dz + dw*dw);
  float r = rsqrtf(ss * (1.f / 1024.f) + 1e-5f);
  int c4 = tid * 4;
  float4 o;
  o.x = fmaxf(dx * r * g[c4+0] + be[c4+0], 0.f);
  o.y = fmaxf(dy * r * g[c4+1] + be[c4+1], 0.f);
  o.z = fmaxf(dz * r * g[c4+2] + be[c4+2], 0.f);
  o.w = fmaxf(dw * r * g[c4+3] + be[c4+3], 0.f);
  ((float4*)(out + ((size_t)b * T_ + t) * 1024))[tid] = o;
}

// ---------------- persistent cooperative LSTM (all 256 steps) ----------------
// VERBATIM the round-8/10/12 version (passed determinism re-validation x3):
// blocks 0..63 layer 0, 64..127 layer 1; weights in VGPRs, c in registers.
// h published via LLC-homed atomic exchanges -> syncthreads (vmcnt drain ==
// LLC completion) -> relaxed flag store. Consumers: designated-wave relaxed
// polls + plain first-touch reads. FROZEN: r7/r9/r11 all failed
// bit-determinism from sub-us-window stale reads when consumers were
// tightened. Do not touch sync structure, poll placement, or s_sleep.
__global__ __launch_bounds__(512)
void lstm_persistent(const ushort* __restrict__ Z0T,   // [T*B,4096] bf16
                     const ushort* __restrict__ whh0,  // [4096,1024]
                     const float* __restrict__ bhh0,
                     const ushort* __restrict__ wih1,  // [4096,1024]
                     const ushort* __restrict__ whh1,  // [4096,1024]
                     const float* __restrict__ bih1,
                     const float* __restrict__ bhh1,
                     ushort* __restrict__ HP,          // [257][16][1024], slot0 zeroed
                     ushort* __restrict__ H1B,         // [256][16][1024]
                     const ushort* __restrict__ ZP,    // 32KB zeros (h1 at t=-1)
                     float* __restrict__ KSUM,         // [S*B,1024] f32
                     int* flag0,                       // [257][64]
                     int* flag1)                       // [256][64]
{
  __shared__ char Ah[65536];
  __shared__ float zs[8][16][16];
  __builtin_amdgcn_fence(__ATOMIC_ACQUIRE, "agent");   // once: clear stale lines
  const int tid = threadIdx.x, w = tid >> 6, l = tid & 63;
  const int lm = l & 15, lq = l >> 4;
  const int g = w & 3, kh = w >> 2;
  const int jb = blockIdx.x & 63;
  const int j0 = jb * 16;
  const int eb = tid >> 4, ej = tid & 15, jf = j0 + ej;   // tid<256 only
  float creg = 0.f;
  float br[4];

  if (blockIdx.x < 64) {
    // ================= layer 0 =================
    short8v wreg[16];
    {
      const int n = g * 1024 + j0 + lm;
      const ushort* wb = whh0 + (size_t)n * 1024 + kh * 512 + lq * 8;
      #pragma unroll
      for (int ks = 0; ks < 16; ++ks) wreg[ks] = *(const short8v*)(wb + ks * 32);
    }
    if (tid < 256) {
      #pragma unroll
      for (int gg = 0; gg < 4; ++gg) br[gg] = bhh0[gg * 1024 + jf];
    }
    for (int t = 0; t < T_; ++t) {
      // prefetch Z0 gate pre-activations (static data) before the spin
      float z0v[4];
      if (tid < 256) {
        const ushort* zp = Z0T + ((size_t)t * 16 + eb) * 4096 + jf;
        #pragma unroll
        for (int gg = 0; gg < 4; ++gg) z0v[gg] = b2f(zp[gg * 1024]);
      }
      if (t > 0) {
        if (w == 0) waitflags64(flag0 + (size_t)t * 64, l);
        __syncthreads();
      }
      const ushort* hin = HP + (size_t)t * 16384;
      #pragma unroll
      for (int it = 0; it < 4; ++it) {
        int g1k = w * 4 + it;             // 0..31 (1KB chunks)
        int kc = g1k * 4 + lq;            // 0..127
        int m = lm ^ (kc & 15);
        glds16(hin + (size_t)m * 1024 + kc * 8, Ah + g1k * 1024);
      }
      __syncthreads();
      {
        f32x4 a0 = {0.f,0.f,0.f,0.f}, a1 = {0.f,0.f,0.f,0.f};
        #pragma unroll
        for (int ks = 0; ks < 16; ks += 2) {
          int kc0 = kh * 64 + ks * 4 + lq;
          int kc1 = kc0 + 4;
          short8v f0 = *(const short8v*)(Ah + kc0 * 256 + ((lm ^ (kc0 & 15)) << 4));
          short8v f1 = *(const short8v*)(Ah + kc1 * 256 + ((lm ^ (kc1 & 15)) << 4));
          a0 = __builtin_amdgcn_mfma_f32_16x16x32_bf16(f0, wreg[ks],     a0, 0, 0, 0);
          a1 = __builtin_amdgcn_mfma_f32_16x16x32_bf16(f1, wreg[ks + 1], a1, 0, 0, 0);
        }
        #pragma unroll
        for (int q = 0; q < 4; ++q) zs[w][lq * 4 + q][lm] = a0[q] + a1[q];
      }
      __syncthreads();
      if (tid < 256) {
        float zi = zs[0][eb][ej] + zs[4][eb][ej] + z0v[0] + br[0];
        float zf = zs[1][eb][ej] + zs[5][eb][ej] + z0v[1] + br[1];
        float zg = zs[2][eb][ej] + zs[6][eb][ej] + z0v[2] + br[2];
        float zo = zs[3][eb][ej] + zs[7][eb][ej] + z0v[3] + br[3];
        float cp = sigm(zf) * creg + sigm(zi) * tanhf(zg);
        creg = cp;
        ushort hb = f2b(sigm(zo) * tanhf(cp));
        publish_pair(HP + (size_t)(t + 1) * 16384 + eb * 1024 + jf, tid, hb);
      }
      __syncthreads();   // vmcnt drain: atomic swaps completed AT THE LLC
      if (tid == 0)
        __hip_atomic_store(flag0 + (size_t)(t + 1) * 64 + jb, 1,
                           __ATOMIC_RELAXED, __HIP_MEMORY_SCOPE_AGENT);
    }
  } else {
    // ================= layer 1 =================
    short8v wreg[32];
    {
      const int n = g * 1024 + j0 + lm;
      const ushort* wb = (kh ? whh1 : wih1) + (size_t)n * 1024 + lq * 8;
      #pragma unroll
      for (int ks = 0; ks < 32; ++ks) wreg[ks] = *(const short8v*)(wb + ks * 32);
    }
    if (tid < 256) {
      #pragma unroll
      for (int gg = 0; gg < 4; ++gg)
        br[gg] = bih1[gg * 1024 + jf] + bhh1[gg * 1024 + jf];
    }
    float ksr = 0.f;
    for (int t = 0; t < T_; ++t) {
      // h0(t) is produced by the (lighter, ahead-running) L0 chain -- usually
      // already flagged. Stage it FIRST, then overlap its read latency with
      // the own-chain flag1 wait (the critical edge).
      if (w == 0) waitflags64(flag0 + (size_t)(t + 1) * 64, l);
      __syncthreads();
      const ushort* h0n = HP + (size_t)(t + 1) * 16384;
      #pragma unroll
      for (int it = 0; it < 4; ++it) {
        int g1k = w * 4 + it;             // chunks 0..31 -> kc 0..127 (h0)
        int kc = g1k * 4 + lq;
        int m = lm ^ (kc & 15);
        glds16(h0n + (size_t)m * 1024 + kc * 8, Ah + g1k * 1024);
      }
      if (w == 1 && t > 0) waitflags64(flag1 + (size_t)(t - 1) * 64, l);
      __syncthreads();   // flag1 confirmed; h0 loads drained per-wave here
      const ushort* h1p = (t > 0) ? (H1B + (size_t)(t - 1) * 16384) : ZP;
      #pragma unroll
      for (int it = 0; it < 4; ++it) {
        int g1k = 32 + w * 4 + it;        // chunks 32..63 -> kc 128..255 (h1)
        int kc = g1k * 4 + lq;
        int m = lm ^ (kc & 15);
        glds16(h1p + (size_t)m * 1024 + (kc - 128) * 8, Ah + g1k * 1024);
      }
      __syncthreads();
      {
        f32x4 a0 = {0.f,0.f,0.f,0.f}, a1 = {0.f,0.f,0.f,0.f};
        #pragma unroll
        for (int ks = 0; ks < 32; ks += 2) {
          int kc0 = kh * 128 + ks * 4 + lq;
          int kc1 = kc0 + 4;
          short8v f0 = *(const short8v*)(Ah + kc0 * 256 + ((lm ^ (kc0 & 15)) << 4));
          short8v f1 = *(const short8v*)(Ah + kc1 * 256 + ((lm ^ (kc1 & 15)) << 4));
          a0 = __builtin_amdgcn_mfma_f32_16x16x32_bf16(f0, wreg[ks],     a0, 0, 0, 0);
          a1 = __builtin_amdgcn_mfma_f32_16x16x32_bf16(f1, wreg[ks + 1], a1, 0, 0, 0);
        }
        #pragma unroll
        for (int q = 0; q < 4; ++q) zs[w][lq * 4 + q][lm] = a0[q] + a1[q];
      }
      __syncthreads();
      if (tid < 256) {
        float zi = zs[0][eb][ej] + zs[4][eb][ej] + br[0];
        float zf = zs[1][eb][ej] + zs[5][eb][ej] + br[1];
        float zg = zs[2][eb][ej] + zs[6][eb][ej] + br[2];
        float zo = zs[3][eb][ej] + zs[7][eb][ej] + br[3];
        float cp = sigm(zf) * creg + sigm(zi) * tanhf(zg);
        creg = cp;
        float hv = sigm(zo) * tanhf(cp);
        ksr += hv;
        publish_pair(H1B + (size_t)t * 16384 + eb * 1024 + jf, tid, f2b(hv));
        if ((t & 15) == 15) {
          KSUM[((size_t)(t >> 4) * 16 + eb) * 1024 + jf] = ksr;   // post-kernel consumer
          ksr = 0.f;
        }
      }
      __syncthreads();   // vmcnt drain: swaps completed at LLC
      if (tid == 0)
        __hip_atomic_store(flag1 + (size_t)t * 64 + jb, 1,
                           __ATOMIC_RELAXED, __HIP_MEMORY_SCOPE_AGENT);
    }
  }
}

// prep_banks: cvt KSUM->bf16 and gather segment-final h1 rows, one launch.
// KSB rows 0-255 = K-input, rows 256-511 = V-input (contiguous for one GEMM).
__global__ __launch_bounds__(256)
void prep_banks(const float* __restrict__ KSUM, ushort* __restrict__ KSB,
                const ushort* __restrict__ H1B)
{
  int r = blockIdx.x;             // 0..255 (s*16+b)
  int c4 = threadIdx.x * 4;
  float4 v = *(const float4*)(KSUM + (size_t)r * 1024 + c4);
  ushort4 o; o.x = f2b(v.x); o.y = f2b(v.y); o.z = f2b(v.z); o.w = f2b(v.w);
  *(ushort4*)(KSB + (size_t)r * 1024 + c4) = o;
  int src = (r >> 4) * 256 + 240 + (r & 15);
  *(ushort4*)(KSB + (size_t)(256 + r) * 1024 + c4) =
      *(const ushort4*)(H1B + (size_t)src * 1024 + c4);
}

// fused attention using folded keys (score = h1 . KK, KK = kbank@Wq) +
// RHB build: RHB[r, 0:1024] = h1, RHB[r, 1024:2048] = bf16(R)
__global__ __launch_bounds__(256)
void attn_rh(const ushort* __restrict__ H1B, const ushort* __restrict__ KKb,
             const ushort* __restrict__ vbank, ushort* __restrict__ RHB)
{
  int row = blockIdx.x;          // t*16 + b
  int t = row >> 4, b = row & 15;
  int si = t >> 4;
  int tid = threadIdx.x, lane = tid & 63, w = tid >> 6;
  __shared__ float sc[16];
  float4 accv = {0.f, 0.f, 0.f, 0.f};
  if (si > 0) {
    const ushort* q = H1B + (size_t)row * 1024;
    for (int s = w; s < si; s += 4) {
      const ushort* kk = KKb + ((size_t)s * 16 + b) * 1024;
      float p = 0.f;
      for (int k = lane; k < 1024; k += 64) p += b2f(q[k]) * b2f(kk[k]);
      #pragma unroll
      for (int off = 32; off; off >>= 1) p += __shfl_down(p, off);
      if (lane == 0) sc[s] = p * SCALE_;
    }
    __syncthreads();
    float mx = -1e30f;
    for (int s = 0; s < si; ++s) mx = fmaxf(mx, sc[s]);
    float den = 0.f;
    for (int s = 0; s < si; ++s) den += expf(sc[s] - mx);
    float inv = 1.f / den;
    for (int s = 0; s < si; ++s) {
      float a = expf(sc[s] - mx) * inv;
      ushort4 vv = *(const ushort4*)(vbank + ((size_t)s * 16 + b) * 1024 + tid * 4);
      accv.x += a * b2f(vv.x); accv.y += a * b2f(vv.y);
      accv.z += a * b2f(vv.z); accv.w += a * b2f(vv.w);
    }
  }
  size_t r = row;
  int c4 = tid * 4;
  ushort4 h4 = *(const ushort4*)(H1B + r * 1024 + c4);
  *(ushort4*)(RHB + r * 2048 + c4) = h4;
  ushort4 rb; rb.x = f2b(accv.x); rb.y = f2b(accv.y);
  rb.z = f2b(accv.z); rb.w = f2b(accv.w);
  *(ushort4*)(RHB + r * 2048 + 1024 + c4) = rb;
}

extern "C" void kernel_launch(void* const* d_in, const int* in_sizes, int n_in,
                              void* d_out, int out_size, void* d_ws, size_t ws_size,
                              hipStream_t stream) {
  const float* x     = (const float*)d_in[0];
  const float* W_ip  = (const float*)d_in[1];
  const float* b_ip  = (const float*)d_in[2];
  const float* g_ip  = (const float*)d_in[3];
  const float* be_ip = (const float*)d_in[4];
  const float* W_ih0 = (const float*)d_in[5];
  const float* W_hh0 = (const float*)d_in[6];
  const float* b_ih0 = (const float*)d_in[7];
  const float* b_hh0 = (const float*)d_in[8];
  const float* W_ih1 = (const float*)d_in[9];
  const float* W_hh1 = (const float*)d_in[10];
  const float* b_ih1 = (const float*)d_in[11];
  const float* b_hh1 = (const float*)d_in[12];
  const float* Wq    = (const float*)d_in[13];
  const float* Wk    = (const float*)d_in[14];
  const float* Wv    = (const float*)d_in[15];
  const float* Wg1   = (const float*)d_in[16];
  const float* bg1   = (const float*)d_in[17];
  const float* Wg2   = (const float*)d_in[18];
  const float* bg2   = (const float*)d_in[19];
  const float* Wo    = (const float*)d_in[20];
  const float* bo    = (const float*)d_in[21];
  const float* Wf    = (const float*)d_in[22];
  const float* bff   = (const float*)d_in[23];
  const float* g_f   = (const float*)d_in[24];
  const float* be_f  = (const float*)d_in[25];
  float* out = (float*)d_out;
  char* ws = (char*)d_ws;
  const size_t MB = (size_t)1 << 20;
  const size_t KB = (size_t)1 << 10;

  // bf16 weight pool (offsets in elements)
  ushort* WB = (ushort*)(ws);
  ushort* wipB  = WB;             // 1M
  ushort* wih0B = WB + 1*1048576; // 4M
  ushort* whh0B = WB + 5*1048576;
  ushort* wih1B = WB + 9*1048576;
  ushort* whh1B = WB + 13*1048576;
  ushort* wqTB  = WB + 17*1048576; // transposed Wq
  ushort* wkB   = WB + 18*1048576;
  ushort* wvB   = WB + 19*1048576;
  ushort* wg1F  = WB + 20*1048576; // folded [Wh|Wr] [1024,2048] (2M)
  ushort* wg2B  = WB + 23*1048576;
  ushort* woB   = WB + 24*1048576;
  ushort* wfB   = WB + 25*1048576; // 2M -> ends 27M elems = 54MB

  ushort* XB   = (ushort*)(ws + 54 * MB);   // 8MB: x bf16, later XPB
  ushort* XPP  = (ushort*)(ws + 62 * MB);   // 8MB: input_proj pre-LN (bf16)
  char*   SCR  = ws + 78 * MB;              // 48MB scratch region
  ushort* Z0T  = (ushort*)SCR;              // 32MB bf16 [T*B,4096] (phase B/C)
  // post-loop overlays (Z0T dead after phase C):
  ushort* RHB  = (ushort*)SCR;              // 16MB [4096,2048]: [h1 | R] then [h1 | out]
  ushort* G1B  = (ushort*)(SCR + 16 * MB);  // 8MB  [4096,1024]
  ushort* MIXB = (ushort*)(SCR + 24 * MB);  // 8MB
  float*  FB   = (float*)(SCR + 32 * MB);   // 16MB
  ushort* H1B  = (ushort*)(ws + 126 * MB);  // 8MB
  ushort* HP   = (ushort*)(ws + 134 * MB);  // 257*32KB = 8.22MB
  char*   ST   = ws + 150 * MB;
  int*    flag0 = (int*)(ST);                     // [257][64] = 65.8KB
  int*    flag1 = (int*)(ST + 68 * KB);           // [256][64] = 64KB
  const ushort* ZPc = (const ushort*)(ST + 132 * KB);   // 32KB zeros
  float*  KSUM = (float*)(ST + 192 * KB);         // 1MB
  ushort* KSB  = (ushort*)(ST + 1216 * KB);       // [512,1024] bf16 = 1MB
  ushort* KBb  = (ushort*)(ST + 2240 * KB);       // [512,1024] bf16 = 1MB
  ushort* VBb  = KBb + 256 * 1024;                //   (kbank | vbank)
  ushort* KKb  = (ushort*)(ST + 3264 * KB);       // [256,1024] bf16 = 0.5MB

  // zero flags + h1(-1) zero-page; HP slot0 zeroed separately
  hipMemsetAsync(ST, 0, 164 * KB, stream);
  hipMemsetAsync(HP, 0, 32 * KB, stream);

  dim3 blk(256);
  // fused weight + input conversion (Wq and Wg1 handled by special kernels)
  {
    CvtJobs J;
    const float* srcs[NJOBS] = { x, W_ip, W_ih0, W_hh0, W_ih1, W_hh1,
                                 Wk, Wv, Wg2, Wo, Wf, nullptr };
    ushort* dsts[NJOBS] = { XB, wipB, wih0B, whh0B, wih1B, whh1B,
                            wkB, wvB, wg2B, woB, wfB, nullptr };
    int n4[NJOBS] = { 1048576, 262144, 1048576, 1048576, 1048576, 1048576,
                      262144, 262144, 262144, 262144, 524288, 0 };
    int c = 0;
    for (int j = 0; j < NJOBS; ++j) {
      J.src[j] = srcs[j] ? srcs[j] : x;
      J.dst[j] = dsts[j] ? dsts[j] : XB;
      J.cum[j] = c;
      c += n4[j];
    }
    J.cum[NJOBS] = c;
    cvt_all<<<dim3((c + 255) / 256), blk, 0, stream>>>(J);
  }
  tr_cvt<<<dim3(16, 16), blk, 0, stream>>>(Wq, wqTB);
  wg1_fold<<<1024, blk, 0, stream>>>(Wg1, wg1F);

  const int BIG = 1 << 30;
  // Phase A: XPP = bf16(x@W_ip^T + b_ip); XB = relu(LN(XPP)) (bf16)
  gemm_bf16<0,0><<<dim3(1024/128, 4096/128), blk, 0, stream>>>(
      XB, wipB, b_ip, nullptr, XPP, 4096, 1024, 1024, 1.f, 1024,
      nullptr, nullptr, wipB, 1.f, BIG);
  ln_relu_bf16<<<4096, blk, 0, stream>>>(XPP, g_ip, be_ip, XB);
  // Phase B: Z0T = XB@W_ih0^T + b_ih0, rows remapped to t*16+b, bf16
  gemm_bf16<0,1><<<dim3(4096/128, 4096/128), blk, 0, stream>>>(
      XB, wih0B, b_ih0, nullptr, Z0T, 4096, 4096, 1024, 1.f, 4096,
      nullptr, nullptr, wih0B, 1.f, BIG);
  // Phase C: single persistent cooperative kernel, all 256 steps (FROZEN)
  {
    void* kargs[] = {
      (void*)&Z0T, (void*)&whh0B, (void*)&b_hh0,
      (void*)&wih1B, (void*)&whh1B, (void*)&b_ih1, (void*)&b_hh1,
      (void*)&HP, (void*)&H1B, (void*)&ZPc, (void*)&KSUM,
      (void*)&flag0, (void*)&flag1
    };
    hipLaunchCooperativeKernel((const void*)lstm_persistent,
                               dim3(128), dim3(512), kargs, 0, stream);
  }
  // Phase D: banks. Merged GEMM: rows<256 -> kbank (Wk, /16), rows>=256 ->
  // vbank (Wv); then KK = kbank@Wq (folded-key trick kills the Q GEMM).
  prep_banks<<<256, blk, 0, stream>>>(KSUM, KSB, H1B);
  gemm_bf16<0,0><<<dim3(1024/128, 512/128), blk, 0, stream>>>(
      KSB, wkB, nullptr, nullptr, KBb, 512, 1024, 1024, 1.f/16.f, 1024,
      nullptr, nullptr, wvB, 1.f, 256);
  gemm_bf16<0,0><<<dim3(1024/128, 256/128), blk, 0, stream>>>(
      KBb, wqTB, nullptr, nullptr, KKb, 256, 1024, 1024, 1.f, 1024,
      nullptr, nullptr, wqTB, 1.f, BIG);
  // Phase E: attention (h1 . KK) + RHB build -> folded gate GEMM (K=2048)
  // -> mix -> Wo (masked, overwrites R half with out) -> Wf -> final LN
  attn_rh<<<4096, blk, 0, stream>>>(H1B, KKb, VBb, RHB);
  gemm_bf16<1,0><<<dim3(1024/128, 4096/128), blk, 0, stream>>>(
      RHB, wg1F, bg1, nullptr, G1B, 4096, 1024, 2048, 1.f, 1024,
      nullptr, nullptr, wg1F, 1.f, BIG);
  gemm_bf16<3,0><<<dim3(1024/128, 4096/128), blk, 0, stream>>>(
      G1B, wg2B, bg2, nullptr, MIXB, 4096, 1024, 1024, 1.f, 1024,
      H1B, RHB + 1024, wg2B, 1.f, BIG);
  gemm_bf16<4,0><<<dim3(1024/128, 4096/128), blk, 0, stream>>>(
      MIXB, woB, bo, nullptr, RHB + 1024, 4096, 1024, 1024, 1.f, 2048,
      nullptr, nullptr, woB, 1.f, BIG);
  gemm_bf16<0,0><<<dim3(1024/128, 4096/128), blk, 0, stream>>>(
      RHB, wfB, bff, FB, nullptr, 4096, 1024, 2048, 1.f, 1024,
      nullptr, nullptr, wfB, 1.f, BIG);
  ln_relu_final<<<4096, blk, 0, stream>>>(FB, g_f, be_f, out);
}